// Round 1
// 851.824 us; speedup vs baseline: 1.0249x; 1.0249x over previous
//
#include <hip/hip_runtime.h>

#define BB_ 4
#define TT_ 8
#define CC_ 64
#define HW 4096
#define UMAP 1024      // floats per (b,c) spectrum map: 32 ky * 16 kx * 2
#define STEP 0.09817477042468103f   // 2*pi/64

// ws float offsets
#define OFF_UXALL 0                                     // 8*256*1024
#define OFF_UH    (OFF_UXALL + TT_*256*UMAP)            // 256*1024
#define OFF_URH   (OFF_UH + 256*UMAP)                   // 256*1024
#define OFF_SX    (OFF_URH + 256*UMAP)                  // 3 slots * 8 t * 256 maps * 1024
#define OFF_SPART (OFF_SX + 3*TT_*256*UMAP)             // 2 slots * 8 ic * 256 maps * 1024
#define OFF_H     (OFF_SPART + 2*8*256*UMAP)
#define OFF_Z     (OFF_H + BB_*CC_*HW)
#define OFF_RH    (OFF_Z + BB_*CC_*HW)
#define OFF_PH    (OFF_RH + BB_*CC_*HW)

// ---------------- init: h = bias, Uh = spectrum of constant map ----------------
__global__ __launch_bounds__(256) void k_init(float* __restrict__ hb,
                                              float* __restrict__ Uh,
                                              const float* __restrict__ bias_h) {
    float v = bias_h[0];
    int blk = blockIdx.x;
    if (blk < 1024) {
        int idx = (blk * 256 + threadIdx.x) * 4;
        *(float4*)(hb + idx) = make_float4(v, v, v, v);
    } else {
        // spectrum of constant v map: only (ky=0,kx=0) = 4096*v/64 = 64*v
        int map = blk - 1024;
        float4 z = make_float4(0.f, 0.f, 0.f, 0.f);
        if (threadIdx.x == 0) z.x = 64.f * v;
        *(float4*)(Uh + (size_t)map * UMAP + threadIdx.x * 4) = z;
    }
}

// ---------------- forward partial DFT stages (input already in LDS su[64*65]) ----
__device__ __forceinline__ void dft_stages(const float* __restrict__ su,
                                           float* __restrict__ FxR, float* __restrict__ FxI,
                                           float* __restrict__ dst) {
    int tid = threadIdx.x;
    int kx = tid & 15, yb = tid >> 4;
    float stc, sts;
    __sincosf(-STEP * (float)kx, &sts, &stc);
    float wr = 1.f, wi = 0.f;
    float aR[4] = {0, 0, 0, 0}, aI[4] = {0, 0, 0, 0};
    for (int x = 0; x < 64; x++) {
        #pragma unroll
        for (int j = 0; j < 4; j++) {
            float v = su[(yb + 16 * j) * 65 + x];
            aR[j] = fmaf(v, wr, aR[j]);
            aI[j] = fmaf(v, wi, aI[j]);
        }
        float t = wr * stc - wi * sts;
        wi = wr * sts + wi * stc;
        wr = t;
    }
    #pragma unroll
    for (int j = 0; j < 4; j++) {
        FxR[(yb + 16 * j) * 16 + kx] = aR[j];
        FxI[(yb + 16 * j) * 16 + kx] = aI[j];
    }
    __syncthreads();
    int kb = tid >> 4;
    float c0, s0, c1, s1;
    __sincosf(-STEP * (float)kb, &s0, &c0);
    __sincosf(-STEP * (float)(kb + 48), &s1, &c1);
    float w0r = 1, w0i = 0, w1r = 1, w1i = 0;
    float A0r = 0, A0i = 0, A1r = 0, A1i = 0;
    for (int y = 0; y < 64; y++) {
        float Fr = FxR[y * 16 + kx], Fi = FxI[y * 16 + kx];
        A0r = fmaf(Fr, w0r, A0r); A0r = fmaf(-Fi, w0i, A0r);
        A0i = fmaf(Fr, w0i, A0i); A0i = fmaf(Fi, w0r, A0i);
        A1r = fmaf(Fr, w1r, A1r); A1r = fmaf(-Fi, w1i, A1r);
        A1i = fmaf(Fr, w1i, A1i); A1i = fmaf(Fi, w1r, A1i);
        float t0 = w0r * c0 - w0i * s0; w0i = w0r * s0 + w0i * c0; w0r = t0;
        float t1 = w1r * c1 - w1i * s1; w1i = w1r * s1 + w1i * c1; w1r = t1;
    }
    const float sc = 1.f / 64.f;
    float2* d2 = (float2*)dst;
    d2[kb * 16 + kx]        = make_float2(A0r * sc, A0i * sc);
    d2[(kb + 16) * 16 + kx] = make_float2(A1r * sc, A1i * sc);
}

// ---------------- batched DFT of all x_t maps (once per launch) ----------------
__global__ __launch_bounds__(256) void k_dft_x(const float* __restrict__ x,
                                               float* __restrict__ Uxall) {
    __shared__ float su[64 * 65];
    __shared__ float FxR[1024], FxI[1024];
    int blk = blockIdx.x;
    int t = blk >> 8, map = blk & 255;
    int b = map >> 6, c = map & 63;
    const float* src = x + (((size_t)b * TT_ + t) * CC_ + c) * HW;
    int tid = threadIdx.x;
    #pragma unroll
    for (int k = 0; k < 4; k++) {
        int off = k * 1024 + tid * 4;
        float4 v = *(const float4*)(src + off);
        int y = off >> 6, xx = off & 63;
        su[y * 65 + xx + 0] = v.x; su[y * 65 + xx + 1] = v.y;
        su[y * 65 + xx + 2] = v.z; su[y * 65 + xx + 3] = v.w;
    }
    __syncthreads();
    dft_stages(su, FxR, FxI, Uxall + ((size_t)t * 256 + map) * UMAP);
}

// ---------------- mix accumulation core ----------------------------------------
__device__ __forceinline__ void mix_load(const float2* __restrict__ W2,
                                         const float2* __restrict__ U2, int i,
                                         float2 w[4], float2 u[4]) {
    const float2* wp = W2 + (size_t)i * 16384;
    const float2* up = U2 + (size_t)i * 512;
    w[0] = wp[0]; w[1] = wp[256]; w[2] = wp[512]; w[3] = wp[768];
    u[0] = up[0]; u[1] = up[32768]; u[2] = up[65536]; u[3] = up[98304];
}

__device__ __forceinline__ void mix_fma(const float2 w[4], const float2 u[4],
                                        float aR[4][4], float aI[4][4]) {
    #pragma unroll
    for (int oo = 0; oo < 4; oo++)
        #pragma unroll
        for (int bb = 0; bb < 4; bb++) {
            aR[oo][bb] = fmaf(u[bb].x, w[oo].x, aR[oo][bb]);
            aR[oo][bb] = fmaf(-u[bb].y, w[oo].y, aR[oo][bb]);
            aI[oo][bb] = fmaf(u[bb].x, w[oo].y, aI[oo][bb]);
            aI[oo][bb] = fmaf(u[bb].y, w[oo].x, aI[oo][bb]);
        }
}

// depth-3 pipeline (used by per-step h-side mixes, niter=8)
__device__ __forceinline__ void mix_accum(const float2* __restrict__ W2,
                                          const float2* __restrict__ U2,
                                          int niter, float aR[4][4], float aI[4][4])
{
    float2 wA[4], uA[4], wB[4], uB[4], wN[4], uN[4];
    mix_load(W2, U2, 0, wA, uA);
    mix_load(W2, U2, 1, wB, uB);
    for (int i = 0; i + 2 < niter; i += 2) {
        mix_load(W2, U2, i + 2, wN, uN);
        mix_fma(wA, uA, aR, aI);
        #pragma unroll
        for (int k = 0; k < 4; k++) { wA[k] = wN[k]; uA[k] = uN[k]; }
        mix_load(W2, U2, i + 3, wN, uN);
        mix_fma(wB, uB, aR, aI);
        #pragma unroll
        for (int k = 0; k < 4; k++) { wB[k] = wN[k]; uB[k] = uN[k]; }
    }
    mix_fma(wA, uA, aR, aI);
    mix_fma(wB, uB, aR, aI);
}

// depth-5 pipeline (look-ahead 4 iterations) for the fixed 64-i upfront mix.
// Rationale: k_mix_x is grid-capped at 3 blocks/CU (768 blocks); VALUBusy=20%
// showed load latency exposed. ~32 loads in flight per wave covers L2 latency.
__device__ __forceinline__ void mix_accum4(const float2* __restrict__ W2,
                                           const float2* __restrict__ U2,
                                           float aR[4][4], float aI[4][4])
{
    float2 w0[4], u0[4], w1[4], u1[4], w2[4], u2[4], w3[4], u3[4], wN[4], uN[4];
    mix_load(W2, U2, 0, w0, u0);
    mix_load(W2, U2, 1, w1, u1);
    mix_load(W2, U2, 2, w2, u2);
    mix_load(W2, U2, 3, w3, u3);
    for (int i = 0; i < 60; i += 4) {
        mix_load(W2, U2, i + 4, wN, uN);
        mix_fma(w0, u0, aR, aI);
        #pragma unroll
        for (int k = 0; k < 4; k++) { w0[k] = wN[k]; u0[k] = uN[k]; }
        mix_load(W2, U2, i + 5, wN, uN);
        mix_fma(w1, u1, aR, aI);
        #pragma unroll
        for (int k = 0; k < 4; k++) { w1[k] = wN[k]; u1[k] = uN[k]; }
        mix_load(W2, U2, i + 6, wN, uN);
        mix_fma(w2, u2, aR, aI);
        #pragma unroll
        for (int k = 0; k < 4; k++) { w2[k] = wN[k]; u2[k] = uN[k]; }
        mix_load(W2, U2, i + 7, wN, uN);
        mix_fma(w3, u3, aR, aI);
        #pragma unroll
        for (int k = 0; k < 4; k++) { w3[k] = wN[k]; u3[k] = uN[k]; }
    }
    mix_fma(w0, u0, aR, aI);
    mix_fma(w1, u1, aR, aI);
    mix_fma(w2, u2, aR, aI);
    mix_fma(w3, u3, aR, aI);
}

// ---------------- upfront: all x-side mixes (layers 0,2,4, all t) ---------------
// blk bits: [li(3)][t(8)][half(2)][og(16)]; full 64-i accumulation, no partials.
// Sx layout: [(li*8+t)*256 + b*64+o][UMAP]
__global__ __launch_bounds__(256) void k_mix_x(
    const float* __restrict__ Uxall,
    const float* __restrict__ sw1, const float* __restrict__ sw2,
    float* __restrict__ Sx)
{
    int blk = blockIdx.x;
    int og = blk & 15;
    int half = (blk >> 4) & 1;
    int t = (blk >> 5) & 7;
    int li = blk >> 8;          // 0,1,2 -> layers 0,2,4
    int l = li * 2;
    int m = threadIdx.x;
    int o0 = og * 4;
    const float2* wt = (const float2*)(half ? sw2 : sw1);
    const float2* W2 = wt + (((size_t)l * 64) * 64 + o0) * 256 + m;
    const float2* U2 = (const float2*)Uxall + ((size_t)t * 256) * 512 + half * 256 + m;
    float aR[4][4], aI[4][4];
    #pragma unroll
    for (int oo = 0; oo < 4; oo++)
        #pragma unroll
        for (int b = 0; b < 4; b++) { aR[oo][b] = 0.f; aI[oo][b] = 0.f; }
    mix_accum4(W2, U2, aR, aI);
    float2* S2 = (float2*)Sx;
    #pragma unroll
    for (int oo = 0; oo < 4; oo++)
        #pragma unroll
        for (int b = 0; b < 4; b++)
            S2[((size_t)(li * 8 + t) * 256 + b * 64 + o0 + oo) * 512 + half * 256 + m]
                = make_float2(aR[oo][b], aI[oo][b]);
}

// ---------------- per-step h-side mix body --------------------------------------
// blk bits: [g][half][ic(8)][og(16)]; 8 i per block.
// Spart layout: [(g*8+ic)*256 + b*64+o][UMAP]
__device__ __forceinline__ void mix_body_h(int blk, int l0, int l1,
    const float* __restrict__ U,
    const float* __restrict__ sw1, const float* __restrict__ sw2,
    float* __restrict__ Spart)
{
    int og = blk & 15;
    int ic = (blk >> 4) & 7;
    int half = (blk >> 7) & 1;
    int g = (blk >> 8) & 1;
    int m = threadIdx.x;
    int o0 = og * 4, ib = ic * 8;
    int l = g ? l1 : l0;
    const float2* wt = (const float2*)(half ? sw2 : sw1);
    const float2* W2 = wt + (((size_t)l * 64 + ib) * 64 + o0) * 256 + m;
    const float2* U2 = (const float2*)U + (size_t)ib * 512 + half * 256 + m;
    float aR[4][4], aI[4][4];
    #pragma unroll
    for (int oo = 0; oo < 4; oo++)
        #pragma unroll
        for (int b = 0; b < 4; b++) { aR[oo][b] = 0.f; aI[oo][b] = 0.f; }
    mix_accum(W2, U2, 8, aR, aI);
    float2* S2 = (float2*)Spart;
    #pragma unroll
    for (int oo = 0; oo < 4; oo++)
        #pragma unroll
        for (int b = 0; b < 4; b++)
            S2[((size_t)(g * 8 + ic) * 256 + b * 64 + o0 + oo) * 512 + half * 256 + m]
                = make_float2(aR[oo][b], aI[oo][b]);
}

// ---------------- 1x1-conv skip v3: register-tiled GEMM -------------------------
// Old skip_v2 was LDS-BW-bound: 128B LDS per 32 fma per thread (4 B/fma-lane).
// v3: thread = 4o x 4px tile, block = 32o x 128px for one (gate, b, oh).
//   per i: 1 conflict-free ds_read_b128 (8-way pt-broadcast) + 1 contiguous
//   global float4 per tensor -> 1 B/fma-lane LDS, 16 fma per 16B LDS read.
// rr bits: [b(2)][oh(1)][pxc(5)] = 256 blocks per gate (same grid as before).
__device__ __forceinline__ void fma16(const float4 w, const float4 u, float acc[4][4]) {
    acc[0][0] = fmaf(u.x, w.x, acc[0][0]); acc[0][1] = fmaf(u.y, w.x, acc[0][1]);
    acc[0][2] = fmaf(u.z, w.x, acc[0][2]); acc[0][3] = fmaf(u.w, w.x, acc[0][3]);
    acc[1][0] = fmaf(u.x, w.y, acc[1][0]); acc[1][1] = fmaf(u.y, w.y, acc[1][1]);
    acc[1][2] = fmaf(u.z, w.y, acc[1][2]); acc[1][3] = fmaf(u.w, w.y, acc[1][3]);
    acc[2][0] = fmaf(u.x, w.z, acc[2][0]); acc[2][1] = fmaf(u.y, w.z, acc[2][1]);
    acc[2][2] = fmaf(u.z, w.z, acc[2][2]); acc[2][3] = fmaf(u.w, w.z, acc[2][3]);
    acc[3][0] = fmaf(u.x, w.w, acc[3][0]); acc[3][1] = fmaf(u.y, w.w, acc[3][1]);
    acc[3][2] = fmaf(u.z, w.w, acc[3][2]); acc[3][3] = fmaf(u.w, w.w, acc[3][3]);
}

__device__ __forceinline__ void skip_gemm(int rr, float* __restrict__ sW,
    const float* __restrict__ uA, long long bsA,
    const float* __restrict__ uB, long long bsB,
    const float* __restrict__ skw, int lA, int lB, float gb,
    float* __restrict__ out)
{
    int pxc = rr & 31, oh = (rr >> 5) & 1, b = rr >> 6;
    int tid = threadIdx.x;
    int ot = tid & 7, pt = tid >> 3;       // 8 o-tiles x 4o, 32 px-tiles x 4px
    // stage sW[k=p*64+i][oc] (k=128, oc=32): 16 KB, fully coalesced
    #pragma unroll
    for (int n = 0; n < 4; n++) {
        int idx = n * 1024 + tid * 4;
        int k = idx >> 5, oc = idx & 31;
        int p = k >> 6, i = k & 63;
        *(float4*)(sW + idx) =
            *(const float4*)(skw + (p ? lB : lA) * 4096 + i * 64 + oh * 32 + oc);
    }
    __syncthreads();
    float acc[4][4];
    #pragma unroll
    for (int oo = 0; oo < 4; oo++)
        #pragma unroll
        for (int q = 0; q < 4; q++) acc[oo][q] = 0.f;
    const float* pa = uA + (long long)b * bsA + pxc * 128 + pt * 4;
    const float* pb = uB + (long long)b * bsB + pxc * 128 + pt * 4;
    const float4* sW4 = (const float4*)sW;   // [128][8] float4
    #pragma unroll 4
    for (int i = 0; i < 64; i++) {
        float4 ua = *(const float4*)(pa + (size_t)i * HW);
        float4 wa = sW4[i * 8 + ot];
        fma16(wa, ua, acc);
        float4 ub = *(const float4*)(pb + (size_t)i * HW);
        float4 wb = sW4[(64 + i) * 8 + ot];
        fma16(wb, ub, acc);
    }
    float* op = out + ((long long)(b * 64 + oh * 32 + ot * 4)) * HW + pxc * 128 + pt * 4;
    #pragma unroll
    for (int oo = 0; oo < 4; oo++) {
        float4 r = make_float4(acc[oo][0] + gb, acc[oo][1] + gb,
                               acc[oo][2] + gb, acc[oo][3] + gb);
        *(float4*)(op + (size_t)oo * HW) = r;
    }
}

// ---------------- fused front kernels: h-side mix + skip ------------------------
__global__ __launch_bounds__(256) void k_front_zr(
    const float* __restrict__ Uh,
    const float* __restrict__ xt, const float* __restrict__ hb,
    const float* __restrict__ sw1, const float* __restrict__ sw2,
    const float* __restrict__ skw, const float* __restrict__ gate_b,
    float* __restrict__ Spart, float* __restrict__ zb, float* __restrict__ rhb)
{
    __shared__ float smem[4096];
    int blk = blockIdx.x;
    if (blk < 512) {
        mix_body_h(blk, 1, 3, Uh, sw1, sw2, Spart);
    } else {
        int r = blk - 512;
        int g = r >> 8;
        skip_gemm(r & 255, smem,
                  xt, (long long)TT_ * CC_ * HW, hb, (long long)CC_ * HW,
                  skw, g ? 2 : 0, g ? 3 : 1, gate_b[g], g ? rhb : zb);
    }
}

__global__ __launch_bounds__(256) void k_front_h(
    const float* __restrict__ Urh,
    const float* __restrict__ xt, const float* __restrict__ rhb,
    const float* __restrict__ sw1, const float* __restrict__ sw2,
    const float* __restrict__ skw, const float* __restrict__ gate_b,
    float* __restrict__ Spart, float* __restrict__ phb)
{
    __shared__ float smem[4096];
    int blk = blockIdx.x;
    if (blk < 256) {
        mix_body_h(blk, 5, 5, Urh, sw1, sw2, Spart);
    } else {
        int r = blk - 256;
        skip_gemm(r, smem,
                  xt, (long long)TT_ * CC_ * HW, rhb, (long long)CC_ * HW,
                  skw, 4, 5, gate_b[2], phb);
    }
}

// ---------------- inverse DFT stage 1 (shared) ----------------------------------
__device__ __forceinline__ void idft_stage1(const float* __restrict__ SR,
                                            const float* __restrict__ SI,
                                            float* __restrict__ GR, float* __restrict__ GI)
{
    int tid = threadIdx.x;
    int kx = tid & 15, yb = tid >> 4;
    #pragma unroll
    for (int j = 0; j < 4; j++) {
        int y = yb + 16 * j;
        float stc, sts;
        __sincosf(STEP * (float)y, &sts, &stc);
        float ar = 0.f, ai = 0.f;
        float wr = 1.f, wi = 0.f;
        for (int k = 0; k < 16; k++) {
            float sr_ = SR[k * 16 + kx], si_ = SI[k * 16 + kx];
            ar = fmaf(sr_, wr, ar); ar = fmaf(-si_, wi, ar);
            ai = fmaf(sr_, wi, ai); ai = fmaf(si_, wr, ai);
            float t = wr * stc - wi * sts; wi = wr * sts + wi * stc; wr = t;
        }
        int q = (3 * y) & 3;
        float w2r = (q == 0) ? 1.f : ((q == 2) ? -1.f : 0.f);
        float w2i = (q == 1) ? 1.f : ((q == 3) ? -1.f : 0.f);
        for (int k = 16; k < 32; k++) {
            float sr_ = SR[k * 16 + kx], si_ = SI[k * 16 + kx];
            ar = fmaf(sr_, w2r, ar); ar = fmaf(-si_, w2i, ar);
            ai = fmaf(sr_, w2i, ai); ai = fmaf(si_, w2r, ai);
            float t = w2r * stc - w2i * sts; w2i = w2r * sts + w2i * stc; w2r = t;
        }
        GR[y * 16 + kx] = ar;
        GI[y * 16 + kx] = ai;
    }
}

// ---------------- back kernel zr: idft + gate epilogue + fused rh forward DFT ---
__global__ __launch_bounds__(256) void k_back_zr(
    const float* __restrict__ Spart, const float* __restrict__ Sx, int t,
    float* __restrict__ zb, float* __restrict__ rhb,
    const float* __restrict__ hb, float* __restrict__ Urh)
{
    __shared__ float smem[6208];
    float* SR = smem;          // 512
    float* SI = smem + 512;    // 512
    float* GR = smem + 1024;   // 1024
    float* GI = smem + 2048;   // 1024
    int g = blockIdx.x >> 8;
    int map = blockIdx.x & 255;
    int tid = threadIdx.x;
    {
        float4 v = ((const float4*)Sx)[((size_t)(g * 8 + t) * 256 + map) * 256 + tid];
        float sxr = v.x, sxi = v.y, syr = v.z, syi = v.w;
        const float4* base = (const float4*)Spart;
        #pragma unroll
        for (int ic = 0; ic < 8; ic++) {
            float4 p = base[((size_t)(g * 8 + ic) * 256 + map) * 256 + tid];
            sxr += p.x; sxi += p.y; syr += p.z; syi += p.w;
        }
        SR[2 * tid] = sxr; SI[2 * tid] = sxi;
        SR[2 * tid + 1] = syr; SI[2 * tid + 1] = syi;
    }
    __syncthreads();
    idft_stage1(SR, SI, GR, GI);
    __syncthreads();
    int x = tid & 63, ybase = tid >> 6;
    float cx, sx;
    __sincosf(STEP * (float)x, &sx, &cx);
    size_t mo = (size_t)map * HW;
    float rhv[16];
    #pragma unroll
    for (int j = 0; j < 16; j++) {
        int y = ybase + 4 * j;
        float acc = GR[y * 16];
        float wr = cx, wi = sx;
        #pragma unroll
        for (int k = 1; k < 16; k++) {
            acc = fmaf(2.f * GR[y * 16 + k], wr, acc);
            acc = fmaf(-2.f * GI[y * 16 + k], wi, acc);
            float t2 = wr * cx - wi * sx; wi = wr * sx + wi * cx; wr = t2;
        }
        float val = acc * (1.f / 64.f);
        int idx = y * 64 + x;
        if (g == 0) {
            float pre = val + zb[mo + idx];
            zb[mo + idx] = 1.f / (1.f + __expf(-pre));
        } else {
            float pre = val + rhb[mo + idx];
            float rr = 1.f / (1.f + __expf(-pre));
            float rh = rr * hb[mo + idx];
            rhb[mo + idx] = rh;
            rhv[j] = rh;
        }
    }
    if (g == 0) return;
    __syncthreads();
    float* su = smem;
    #pragma unroll
    for (int j = 0; j < 16; j++) {
        int y = ybase + 4 * j;
        su[y * 65 + x] = rhv[j];
    }
    __syncthreads();
    dft_stages(su, smem + 4160, smem + 5184, Urh + (size_t)map * UMAP);
}

// ---------------- back kernel h: idft + GRU update + fused h forward DFT --------
__global__ __launch_bounds__(256) void k_back_h(
    const float* __restrict__ Spart, const float* __restrict__ Sx, int t,
    const float* __restrict__ zb, const float* __restrict__ phb,
    float* __restrict__ hb, float* __restrict__ Uh)
{
    __shared__ float smem[6208];
    float* SR = smem;
    float* SI = smem + 512;
    float* GR = smem + 1024;
    float* GI = smem + 2048;
    int map = blockIdx.x & 255;
    int tid = threadIdx.x;
    {
        float4 v = ((const float4*)Sx)[((size_t)(2 * 8 + t) * 256 + map) * 256 + tid];
        float sxr = v.x, sxi = v.y, syr = v.z, syi = v.w;
        const float4* base = (const float4*)Spart;
        #pragma unroll
        for (int ic = 0; ic < 8; ic++) {
            float4 p = base[((size_t)ic * 256 + map) * 256 + tid];
            sxr += p.x; sxi += p.y; syr += p.z; syi += p.w;
        }
        SR[2 * tid] = sxr; SI[2 * tid] = sxi;
        SR[2 * tid + 1] = syr; SI[2 * tid + 1] = syi;
    }
    __syncthreads();
    idft_stage1(SR, SI, GR, GI);
    __syncthreads();
    int x = tid & 63, ybase = tid >> 6;
    float cx, sx;
    __sincosf(STEP * (float)x, &sx, &cx);
    size_t mo = (size_t)map * HW;
    float hv[16];
    #pragma unroll
    for (int j = 0; j < 16; j++) {
        int y = ybase + 4 * j;
        float acc = GR[y * 16];
        float wr = cx, wi = sx;
        #pragma unroll
        for (int k = 1; k < 16; k++) {
            acc = fmaf(2.f * GR[y * 16 + k], wr, acc);
            acc = fmaf(-2.f * GI[y * 16 + k], wi, acc);
            float t2 = wr * cx - wi * sx; wi = wr * sx + wi * cx; wr = t2;
        }
        float val = acc * (1.f / 64.f);
        int idx = y * 64 + x;
        float pre = val + phb[mo + idx];
        float hh = (pre > 0.f) ? 1.0507009873554805f * pre
                               : 1.7580993408473766f * (__expf(pre) - 1.f);
        float z = zb[mo + idx];
        float hn = fmaf(z, hh - hb[mo + idx], hb[mo + idx]);
        hb[mo + idx] = hn;
        hv[j] = hn;
    }
    __syncthreads();
    float* su = smem;
    #pragma unroll
    for (int j = 0; j < 16; j++) {
        int y = ybase + 4 * j;
        su[y * 65 + x] = hv[j];
    }
    __syncthreads();
    dft_stages(su, smem + 4160, smem + 5184, Uh + (size_t)map * UMAP);
}

extern "C" void kernel_launch(void* const* d_in, const int* in_sizes, int n_in,
                              void* d_out, int out_size, void* d_ws, size_t ws_size,
                              hipStream_t stream)
{
    (void)in_sizes; (void)n_in; (void)out_size; (void)ws_size;
    const float* x   = (const float*)d_in[0];
    const float* sw1 = (const float*)d_in[1];
    const float* sw2 = (const float*)d_in[2];
    const float* skw = (const float*)d_in[3];
    const float* gb  = (const float*)d_in[4];
    const float* bh  = (const float*)d_in[5];
    float* ws    = (float*)d_ws;
    float* Uxall = ws + OFF_UXALL;
    float* Uh    = ws + OFF_UH;
    float* Urh   = ws + OFF_URH;
    float* Sx    = ws + OFF_SX;
    float* Sp    = ws + OFF_SPART;
    float* hb    = ws + OFF_H;
    float* zb    = ws + OFF_Z;
    float* rhb   = ws + OFF_RH;
    float* phb   = ws + OFF_PH;

    k_init<<<1280, 256, 0, stream>>>(hb, Uh, bh);
    k_dft_x<<<2048, 256, 0, stream>>>(x, Uxall);
    k_mix_x<<<768, 256, 0, stream>>>(Uxall, sw1, sw2, Sx);
    for (int t = 0; t < TT_; t++) {
        const float* xt = x + (size_t)t * CC_ * HW;
        k_front_zr<<<1024, 256, 0, stream>>>(Uh, xt, hb, sw1, sw2, skw, gb,
                                             Sp, zb, rhb);
        k_back_zr<<<512, 256, 0, stream>>>(Sp, Sx, t, zb, rhb, hb, Urh);
        k_front_h<<<512, 256, 0, stream>>>(Urh, xt, rhb, sw1, sw2, skw, gb,
                                           Sp, phb);
        k_back_h<<<256, 256, 0, stream>>>(Sp, Sx, t, zb, phb, hb, Uh);
    }
    hipMemcpyAsync(d_out, hb, (size_t)BB_ * CC_ * HW * sizeof(float),
                   hipMemcpyDeviceToDevice, stream);
}

// Round 2
// 787.248 us; speedup vs baseline: 1.1089x; 1.0820x over previous
//
#include <hip/hip_runtime.h>

#define BB_ 4
#define TT_ 8
#define CC_ 64
#define HW 4096
#define UMAP 1024      // floats per (b,c) spectrum map: 32 ky * 16 kx * 2
#define STEP 0.09817477042468103f   // 2*pi/64

// ws float offsets
#define OFF_UXALL 0                                     // 8*256*1024
#define OFF_UH    (OFF_UXALL + TT_*256*UMAP)            // 256*1024
#define OFF_URH   (OFF_UH + 256*UMAP)                   // 256*1024
#define OFF_SX    (OFF_URH + 256*UMAP)                  // 3 slots * 8 t * 256 maps * 1024
#define OFF_SPART (OFF_SX + 3*TT_*256*UMAP)             // 2 slots * 8 ic * 256 maps * 1024
#define OFF_H     (OFF_SPART + 2*8*256*UMAP)
#define OFF_Z     (OFF_H + BB_*CC_*HW)
#define OFF_RH    (OFF_Z + BB_*CC_*HW)
#define OFF_PH    (OFF_RH + BB_*CC_*HW)

// ---------------- init: h = bias, Uh = spectrum of constant map ----------------
__global__ __launch_bounds__(256) void k_init(float* __restrict__ hb,
                                              float* __restrict__ Uh,
                                              const float* __restrict__ bias_h) {
    float v = bias_h[0];
    int blk = blockIdx.x;
    if (blk < 1024) {
        int idx = (blk * 256 + threadIdx.x) * 4;
        *(float4*)(hb + idx) = make_float4(v, v, v, v);
    } else {
        // spectrum of constant v map: only (ky=0,kx=0) = 4096*v/64 = 64*v
        int map = blk - 1024;
        float4 z = make_float4(0.f, 0.f, 0.f, 0.f);
        if (threadIdx.x == 0) z.x = 64.f * v;
        *(float4*)(Uh + (size_t)map * UMAP + threadIdx.x * 4) = z;
    }
}

// ---------------- forward partial DFT stages, 256-thread variant ----------------
__device__ __forceinline__ void dft_stages(const float* __restrict__ su,
                                           float* __restrict__ FxR, float* __restrict__ FxI,
                                           float* __restrict__ dst) {
    int tid = threadIdx.x;
    int kx = tid & 15, yb = tid >> 4;
    float stc, sts;
    __sincosf(-STEP * (float)kx, &sts, &stc);
    float wr = 1.f, wi = 0.f;
    float aR[4] = {0, 0, 0, 0}, aI[4] = {0, 0, 0, 0};
    for (int x = 0; x < 64; x++) {
        #pragma unroll
        for (int j = 0; j < 4; j++) {
            float v = su[(yb + 16 * j) * 65 + x];
            aR[j] = fmaf(v, wr, aR[j]);
            aI[j] = fmaf(v, wi, aI[j]);
        }
        float t = wr * stc - wi * sts;
        wi = wr * sts + wi * stc;
        wr = t;
    }
    #pragma unroll
    for (int j = 0; j < 4; j++) {
        FxR[(yb + 16 * j) * 16 + kx] = aR[j];
        FxI[(yb + 16 * j) * 16 + kx] = aI[j];
    }
    __syncthreads();
    int kb = tid >> 4;
    float c0, s0, c1, s1;
    __sincosf(-STEP * (float)kb, &s0, &c0);
    __sincosf(-STEP * (float)(kb + 48), &s1, &c1);
    float w0r = 1, w0i = 0, w1r = 1, w1i = 0;
    float A0r = 0, A0i = 0, A1r = 0, A1i = 0;
    for (int y = 0; y < 64; y++) {
        float Fr = FxR[y * 16 + kx], Fi = FxI[y * 16 + kx];
        A0r = fmaf(Fr, w0r, A0r); A0r = fmaf(-Fi, w0i, A0r);
        A0i = fmaf(Fr, w0i, A0i); A0i = fmaf(Fi, w0r, A0i);
        A1r = fmaf(Fr, w1r, A1r); A1r = fmaf(-Fi, w1i, A1r);
        A1i = fmaf(Fr, w1i, A1i); A1i = fmaf(Fi, w1r, A1i);
        float t0 = w0r * c0 - w0i * s0; w0i = w0r * s0 + w0i * c0; w0r = t0;
        float t1 = w1r * c1 - w1i * s1; w1i = w1r * s1 + w1i * c1; w1r = t1;
    }
    const float sc = 1.f / 64.f;
    float2* d2 = (float2*)dst;
    d2[kb * 16 + kx]        = make_float2(A0r * sc, A0i * sc);
    d2[(kb + 16) * 16 + kx] = make_float2(A1r * sc, A1i * sc);
}

// ---------------- forward DFT stages, 512-thread variant ------------------------
__device__ __forceinline__ void dft_stages_512(const float* __restrict__ su,
                                               float* __restrict__ FxR, float* __restrict__ FxI,
                                               float* __restrict__ dst) {
    int tid = threadIdx.x;
    int kx = tid & 15, yb = tid >> 4;            // yb 0..31
    float stc, sts;
    __sincosf(-STEP * (float)kx, &sts, &stc);
    float wr = 1.f, wi = 0.f;
    float aR[2] = {0, 0}, aI[2] = {0, 0};
    for (int x = 0; x < 64; x++) {
        #pragma unroll
        for (int j = 0; j < 2; j++) {
            float v = su[(yb + 32 * j) * 65 + x];
            aR[j] = fmaf(v, wr, aR[j]);
            aI[j] = fmaf(v, wi, aI[j]);
        }
        float t = wr * stc - wi * sts;
        wi = wr * sts + wi * stc;
        wr = t;
    }
    #pragma unroll
    for (int j = 0; j < 2; j++) {
        FxR[(yb + 32 * j) * 16 + kx] = aR[j];
        FxI[(yb + 32 * j) * 16 + kx] = aI[j];
    }
    __syncthreads();
    int kb = tid >> 4;                           // 0..31 = output row
    int ky = (kb < 16) ? kb : kb + 32;           // rows 16..31 hold ky 48..63
    float c0, s0;
    __sincosf(-STEP * (float)ky, &s0, &c0);
    float w0r = 1, w0i = 0, A0r = 0, A0i = 0;
    for (int y = 0; y < 64; y++) {
        float Fr = FxR[y * 16 + kx], Fi = FxI[y * 16 + kx];
        A0r = fmaf(Fr, w0r, A0r); A0r = fmaf(-Fi, w0i, A0r);
        A0i = fmaf(Fr, w0i, A0i); A0i = fmaf(Fi, w0r, A0i);
        float t0 = w0r * c0 - w0i * s0; w0i = w0r * s0 + w0i * c0; w0r = t0;
    }
    const float sc = 1.f / 64.f;
    ((float2*)dst)[kb * 16 + kx] = make_float2(A0r * sc, A0i * sc);
}

// ---------------- batched DFT of all x_t maps (once per launch) ----------------
__global__ __launch_bounds__(256) void k_dft_x(const float* __restrict__ x,
                                               float* __restrict__ Uxall) {
    __shared__ float su[64 * 65];
    __shared__ float FxR[1024], FxI[1024];
    int blk = blockIdx.x;
    int t = blk >> 8, map = blk & 255;
    int b = map >> 6, c = map & 63;
    const float* src = x + (((size_t)b * TT_ + t) * CC_ + c) * HW;
    int tid = threadIdx.x;
    #pragma unroll
    for (int k = 0; k < 4; k++) {
        int off = k * 1024 + tid * 4;
        float4 v = *(const float4*)(src + off);
        int y = off >> 6, xx = off & 63;
        su[y * 65 + xx + 0] = v.x; su[y * 65 + xx + 1] = v.y;
        su[y * 65 + xx + 2] = v.z; su[y * 65 + xx + 3] = v.w;
    }
    __syncthreads();
    dft_stages(su, FxR, FxI, Uxall + ((size_t)t * 256 + map) * UMAP);
}

// ---------------- mix accumulation core ----------------------------------------
__device__ __forceinline__ void mix_load(const float2* __restrict__ W2,
                                         const float2* __restrict__ U2, int i,
                                         float2 w[4], float2 u[4]) {
    const float2* wp = W2 + (size_t)i * 16384;
    const float2* up = U2 + (size_t)i * 512;
    w[0] = wp[0]; w[1] = wp[256]; w[2] = wp[512]; w[3] = wp[768];
    u[0] = up[0]; u[1] = up[32768]; u[2] = up[65536]; u[3] = up[98304];
}

__device__ __forceinline__ void mix_fma(const float2 w[4], const float2 u[4],
                                        float aR[4][4], float aI[4][4]) {
    #pragma unroll
    for (int oo = 0; oo < 4; oo++)
        #pragma unroll
        for (int bb = 0; bb < 4; bb++) {
            aR[oo][bb] = fmaf(u[bb].x, w[oo].x, aR[oo][bb]);
            aR[oo][bb] = fmaf(-u[bb].y, w[oo].y, aR[oo][bb]);
            aI[oo][bb] = fmaf(u[bb].x, w[oo].y, aI[oo][bb]);
            aI[oo][bb] = fmaf(u[bb].y, w[oo].x, aI[oo][bb]);
        }
}

// depth-3 pipeline (used by per-step h-side mixes, niter=8)
__device__ __forceinline__ void mix_accum(const float2* __restrict__ W2,
                                          const float2* __restrict__ U2,
                                          int niter, float aR[4][4], float aI[4][4])
{
    float2 wA[4], uA[4], wB[4], uB[4], wN[4], uN[4];
    mix_load(W2, U2, 0, wA, uA);
    mix_load(W2, U2, 1, wB, uB);
    for (int i = 0; i + 2 < niter; i += 2) {
        mix_load(W2, U2, i + 2, wN, uN);
        mix_fma(wA, uA, aR, aI);
        #pragma unroll
        for (int k = 0; k < 4; k++) { wA[k] = wN[k]; uA[k] = uN[k]; }
        mix_load(W2, U2, i + 3, wN, uN);
        mix_fma(wB, uB, aR, aI);
        #pragma unroll
        for (int k = 0; k < 4; k++) { wB[k] = wN[k]; uB[k] = uN[k]; }
    }
    mix_fma(wA, uA, aR, aI);
    mix_fma(wB, uB, aR, aI);
}

// ---------------- upfront: all x-side mixes (layers 0,2,4, all t) ---------------
// v3: 512-thread blocks, K split in half across tid>>8 with LDS reduce (occupancy
// 12 -> 24 waves/CU), and lane remap so each wave covers 16m x 2og x 2t: the U
// address is og-independent and the W address is t-independent -> 2x same-address
// dedup on both operand streams (L1/L2 request traffic halves).
// blk bits: [li(3)][half(1)][op(3)][tp(2)][mq(2)] = 768 blocks.
__global__ __launch_bounds__(512, 4) void k_mix_x(
    const float* __restrict__ Uxall,
    const float* __restrict__ sw1, const float* __restrict__ sw2,
    float* __restrict__ Sx)
{
    __shared__ float2 red2[16 * 256];   // 32 KB
    int blk = blockIdx.x;
    int mq = blk & 3;
    int tp = (blk >> 2) & 3;
    int op = (blk >> 4) & 7;
    int half = (blk >> 7) & 1;
    int li = blk >> 8;          // 0,1,2 -> layers 0,2,4
    int l = li * 2;
    int tid = threadIdx.x;
    int kc = tid >> 8;          // K-half: i in [kc*32, kc*32+32)
    int r = tid & 255;
    int ml = r & 15, og1 = (r >> 4) & 1, t1 = (r >> 5) & 1, wq = r >> 6;
    int m = mq * 64 + wq * 16 + ml;
    int o0 = (op * 2 + og1) * 4;
    int t = tp * 2 + t1;
    const float2* wt = (const float2*)(half ? sw2 : sw1);
    const float2* W2 = wt + ((size_t)(l * 4096 + o0)) * 256 + m + (size_t)kc * 32 * 16384;
    const float2* U2 = (const float2*)Uxall + (size_t)t * 131072 + half * 256 + m
                       + (size_t)kc * 32 * 512;
    float aR[4][4], aI[4][4];
    #pragma unroll
    for (int oo = 0; oo < 4; oo++)
        #pragma unroll
        for (int b = 0; b < 4; b++) { aR[oo][b] = 0.f; aI[oo][b] = 0.f; }
    #pragma unroll 4
    for (int i = 0; i < 32; ++i) {
        float2 w[4], u[4];
        mix_load(W2, U2, i, w, u);
        mix_fma(w, u, aR, aI);
    }
    if (kc) {
        #pragma unroll
        for (int oo = 0; oo < 4; oo++)
            #pragma unroll
            for (int b = 0; b < 4; b++)
                red2[(oo * 4 + b) * 256 + r] = make_float2(aR[oo][b], aI[oo][b]);
    }
    __syncthreads();
    if (kc == 0) {
        float2* S2 = (float2*)Sx;
        #pragma unroll
        for (int oo = 0; oo < 4; oo++)
            #pragma unroll
            for (int b = 0; b < 4; b++) {
                float2 p = red2[(oo * 4 + b) * 256 + r];
                S2[((size_t)(li * 8 + t) * 256 + b * 64 + o0 + oo) * 512 + half * 256 + m]
                    = make_float2(aR[oo][b] + p.x, aI[oo][b] + p.y);
            }
    }
}

// ---------------- per-step h-side mix body --------------------------------------
// blk bits: [g][half][ic(8)][og(16)]; 8 i per block.
// Spart layout: [(g*8+ic)*256 + b*64+o][UMAP]
__device__ __forceinline__ void mix_body_h(int blk, int l0, int l1,
    const float* __restrict__ U,
    const float* __restrict__ sw1, const float* __restrict__ sw2,
    float* __restrict__ Spart)
{
    int og = blk & 15;
    int ic = (blk >> 4) & 7;
    int half = (blk >> 7) & 1;
    int g = (blk >> 8) & 1;
    int m = threadIdx.x;
    int o0 = og * 4, ib = ic * 8;
    int l = g ? l1 : l0;
    const float2* wt = (const float2*)(half ? sw2 : sw1);
    const float2* W2 = wt + (((size_t)l * 64 + ib) * 64 + o0) * 256 + m;
    const float2* U2 = (const float2*)U + (size_t)ib * 512 + half * 256 + m;
    float aR[4][4], aI[4][4];
    #pragma unroll
    for (int oo = 0; oo < 4; oo++)
        #pragma unroll
        for (int b = 0; b < 4; b++) { aR[oo][b] = 0.f; aI[oo][b] = 0.f; }
    mix_accum(W2, U2, 8, aR, aI);
    float2* S2 = (float2*)Spart;
    #pragma unroll
    for (int oo = 0; oo < 4; oo++)
        #pragma unroll
        for (int b = 0; b < 4; b++)
            S2[((size_t)(g * 8 + ic) * 256 + b * 64 + o0 + oo) * 512 + half * 256 + m]
                = make_float2(aR[oo][b], aI[oo][b]);
}

// ---------------- 1x1-conv skip: register-tiled GEMM ----------------------------
// thread = 4o x 4px tile, block = 32o x 128px for one (gate, b, oh).
// rr bits: [b(2)][oh(1)][pxc(5)] = 256 blocks per gate.
__device__ __forceinline__ void fma16(const float4 w, const float4 u, float acc[4][4]) {
    acc[0][0] = fmaf(u.x, w.x, acc[0][0]); acc[0][1] = fmaf(u.y, w.x, acc[0][1]);
    acc[0][2] = fmaf(u.z, w.x, acc[0][2]); acc[0][3] = fmaf(u.w, w.x, acc[0][3]);
    acc[1][0] = fmaf(u.x, w.y, acc[1][0]); acc[1][1] = fmaf(u.y, w.y, acc[1][1]);
    acc[1][2] = fmaf(u.z, w.y, acc[1][2]); acc[1][3] = fmaf(u.w, w.y, acc[1][3]);
    acc[2][0] = fmaf(u.x, w.z, acc[2][0]); acc[2][1] = fmaf(u.y, w.z, acc[2][1]);
    acc[2][2] = fmaf(u.z, w.z, acc[2][2]); acc[2][3] = fmaf(u.w, w.z, acc[2][3]);
    acc[3][0] = fmaf(u.x, w.w, acc[3][0]); acc[3][1] = fmaf(u.y, w.w, acc[3][1]);
    acc[3][2] = fmaf(u.z, w.w, acc[3][2]); acc[3][3] = fmaf(u.w, w.w, acc[3][3]);
}

__device__ __forceinline__ void skip_gemm(int rr, float* __restrict__ sW,
    const float* __restrict__ uA, long long bsA,
    const float* __restrict__ uB, long long bsB,
    const float* __restrict__ skw, int lA, int lB, float gb,
    float* __restrict__ out)
{
    int pxc = rr & 31, oh = (rr >> 5) & 1, b = rr >> 6;
    int tid = threadIdx.x;
    int ot = tid & 7, pt = tid >> 3;       // 8 o-tiles x 4o, 32 px-tiles x 4px
    // stage sW[k=p*64+i][oc] (k=128, oc=32): 16 KB, fully coalesced
    #pragma unroll
    for (int n = 0; n < 4; n++) {
        int idx = n * 1024 + tid * 4;
        int k = idx >> 5, oc = idx & 31;
        int p = k >> 6, i = k & 63;
        *(float4*)(sW + idx) =
            *(const float4*)(skw + (p ? lB : lA) * 4096 + i * 64 + oh * 32 + oc);
    }
    __syncthreads();
    float acc[4][4];
    #pragma unroll
    for (int oo = 0; oo < 4; oo++)
        #pragma unroll
        for (int q = 0; q < 4; q++) acc[oo][q] = 0.f;
    const float* pa = uA + (long long)b * bsA + pxc * 128 + pt * 4;
    const float* pb = uB + (long long)b * bsB + pxc * 128 + pt * 4;
    const float4* sW4 = (const float4*)sW;   // [128][8] float4
    #pragma unroll 4
    for (int i = 0; i < 64; i++) {
        float4 ua = *(const float4*)(pa + (size_t)i * HW);
        float4 wa = sW4[i * 8 + ot];
        fma16(wa, ua, acc);
        float4 ub = *(const float4*)(pb + (size_t)i * HW);
        float4 wb = sW4[(64 + i) * 8 + ot];
        fma16(wb, ub, acc);
    }
    float* op = out + ((long long)(b * 64 + oh * 32 + ot * 4)) * HW + pxc * 128 + pt * 4;
    #pragma unroll
    for (int oo = 0; oo < 4; oo++) {
        float4 r = make_float4(acc[oo][0] + gb, acc[oo][1] + gb,
                               acc[oo][2] + gb, acc[oo][3] + gb);
        *(float4*)(op + (size_t)oo * HW) = r;
    }
}

// ---------------- fused front kernels: h-side mix + skip ------------------------
__global__ __launch_bounds__(256) void k_front_zr(
    const float* __restrict__ Uh,
    const float* __restrict__ xt, const float* __restrict__ hb,
    const float* __restrict__ sw1, const float* __restrict__ sw2,
    const float* __restrict__ skw, const float* __restrict__ gate_b,
    float* __restrict__ Spart, float* __restrict__ zb, float* __restrict__ rhb)
{
    __shared__ float smem[4096];
    int blk = blockIdx.x;
    if (blk < 512) {
        mix_body_h(blk, 1, 3, Uh, sw1, sw2, Spart);
    } else {
        int r = blk - 512;
        int g = r >> 8;
        skip_gemm(r & 255, smem,
                  xt, (long long)TT_ * CC_ * HW, hb, (long long)CC_ * HW,
                  skw, g ? 2 : 0, g ? 3 : 1, gate_b[g], g ? rhb : zb);
    }
}

__global__ __launch_bounds__(256) void k_front_h(
    const float* __restrict__ Urh,
    const float* __restrict__ xt, const float* __restrict__ rhb,
    const float* __restrict__ sw1, const float* __restrict__ sw2,
    const float* __restrict__ skw, const float* __restrict__ gate_b,
    float* __restrict__ Spart, float* __restrict__ phb)
{
    __shared__ float smem[4096];
    int blk = blockIdx.x;
    if (blk < 256) {
        mix_body_h(blk, 5, 5, Urh, sw1, sw2, Spart);
    } else {
        int r = blk - 256;
        skip_gemm(r, smem,
                  xt, (long long)TT_ * CC_ * HW, rhb, (long long)CC_ * HW,
                  skw, 4, 5, gate_b[2], phb);
    }
}

// ---------------- inverse DFT stage 1, 512-thread variant -----------------------
__device__ __forceinline__ void idft_stage1_512(const float* __restrict__ SR,
                                                const float* __restrict__ SI,
                                                float* __restrict__ GR, float* __restrict__ GI)
{
    int tid = threadIdx.x;
    int kx = tid & 15, yb = tid >> 4;        // yb 0..31
    #pragma unroll
    for (int j = 0; j < 2; j++) {
        int y = yb + 32 * j;
        float stc, sts;
        __sincosf(STEP * (float)y, &sts, &stc);
        float ar = 0.f, ai = 0.f;
        float wr = 1.f, wi = 0.f;
        for (int k = 0; k < 16; k++) {
            float sr_ = SR[k * 16 + kx], si_ = SI[k * 16 + kx];
            ar = fmaf(sr_, wr, ar); ar = fmaf(-si_, wi, ar);
            ai = fmaf(sr_, wi, ai); ai = fmaf(si_, wr, ai);
            float t = wr * stc - wi * sts; wi = wr * sts + wi * stc; wr = t;
        }
        int q = (3 * y) & 3;
        float w2r = (q == 0) ? 1.f : ((q == 2) ? -1.f : 0.f);
        float w2i = (q == 1) ? 1.f : ((q == 3) ? -1.f : 0.f);
        for (int k = 16; k < 32; k++) {
            float sr_ = SR[k * 16 + kx], si_ = SI[k * 16 + kx];
            ar = fmaf(sr_, w2r, ar); ar = fmaf(-si_, w2i, ar);
            ai = fmaf(sr_, w2i, ai); ai = fmaf(si_, w2r, ai);
            float t = w2r * stc - w2i * sts; w2i = w2r * sts + w2i * stc; w2r = t;
        }
        GR[y * 16 + kx] = ar;
        GI[y * 16 + kx] = ai;
    }
}

// ---------------- back kernel zr (512 thr): idft + gates + fused rh DFT ---------
__global__ __launch_bounds__(512) void k_back_zr(
    const float* __restrict__ Spart, const float* __restrict__ Sx, int t,
    float* __restrict__ zb, float* __restrict__ rhb,
    const float* __restrict__ hb, float* __restrict__ Urh)
{
    __shared__ float smem[6208];
    float* SR = smem;          // 512
    float* SI = smem + 512;    // 512
    float* GR = smem + 1024;   // 1024
    float* GI = smem + 2048;   // 1024
    int g = blockIdx.x >> 8;
    int map = blockIdx.x & 255;
    int tid = threadIdx.x;
    {
        float2 v = ((const float2*)Sx)[((size_t)(g * 8 + t) * 256 + map) * 512 + tid];
        float sr = v.x, si = v.y;
        const float2* base = (const float2*)Spart;
        #pragma unroll
        for (int ic = 0; ic < 8; ic++) {
            float2 p = base[((size_t)(g * 8 + ic) * 256 + map) * 512 + tid];
            sr += p.x; si += p.y;
        }
        SR[tid] = sr; SI[tid] = si;
    }
    __syncthreads();
    idft_stage1_512(SR, SI, GR, GI);
    __syncthreads();
    int x = tid & 63, ybase = tid >> 6;      // ybase 0..7
    float cx, sx;
    __sincosf(STEP * (float)x, &sx, &cx);
    size_t mo = (size_t)map * HW;
    float rhv[8];
    #pragma unroll
    for (int j = 0; j < 8; j++) {
        int y = ybase + 8 * j;
        float acc = GR[y * 16];
        float wr = cx, wi = sx;
        #pragma unroll
        for (int k = 1; k < 16; k++) {
            acc = fmaf(2.f * GR[y * 16 + k], wr, acc);
            acc = fmaf(-2.f * GI[y * 16 + k], wi, acc);
            float t2 = wr * cx - wi * sx; wi = wr * sx + wi * cx; wr = t2;
        }
        float val = acc * (1.f / 64.f);
        int idx = y * 64 + x;
        if (g == 0) {
            float pre = val + zb[mo + idx];
            zb[mo + idx] = 1.f / (1.f + __expf(-pre));
        } else {
            float pre = val + rhb[mo + idx];
            float rr = 1.f / (1.f + __expf(-pre));
            float rh = rr * hb[mo + idx];
            rhb[mo + idx] = rh;
            rhv[j] = rh;
        }
    }
    if (g == 0) return;
    __syncthreads();
    float* su = smem;
    #pragma unroll
    for (int j = 0; j < 8; j++) {
        int y = ybase + 8 * j;
        su[y * 65 + x] = rhv[j];
    }
    __syncthreads();
    dft_stages_512(su, smem + 4160, smem + 5184, Urh + (size_t)map * UMAP);
}

// ---------------- back kernel h (512 thr): idft + GRU update + fused h DFT ------
__global__ __launch_bounds__(512) void k_back_h(
    const float* __restrict__ Spart, const float* __restrict__ Sx, int t,
    const float* __restrict__ zb, const float* __restrict__ phb,
    float* __restrict__ hb, float* __restrict__ Uh)
{
    __shared__ float smem[6208];
    float* SR = smem;
    float* SI = smem + 512;
    float* GR = smem + 1024;
    float* GI = smem + 2048;
    int map = blockIdx.x & 255;
    int tid = threadIdx.x;
    {
        float2 v = ((const float2*)Sx)[((size_t)(2 * 8 + t) * 256 + map) * 512 + tid];
        float sr = v.x, si = v.y;
        const float2* base = (const float2*)Spart;
        #pragma unroll
        for (int ic = 0; ic < 8; ic++) {
            float2 p = base[((size_t)ic * 256 + map) * 512 + tid];
            sr += p.x; si += p.y;
        }
        SR[tid] = sr; SI[tid] = si;
    }
    __syncthreads();
    idft_stage1_512(SR, SI, GR, GI);
    __syncthreads();
    int x = tid & 63, ybase = tid >> 6;
    float cx, sx;
    __sincosf(STEP * (float)x, &sx, &cx);
    size_t mo = (size_t)map * HW;
    float hv[8];
    #pragma unroll
    for (int j = 0; j < 8; j++) {
        int y = ybase + 8 * j;
        float acc = GR[y * 16];
        float wr = cx, wi = sx;
        #pragma unroll
        for (int k = 1; k < 16; k++) {
            acc = fmaf(2.f * GR[y * 16 + k], wr, acc);
            acc = fmaf(-2.f * GI[y * 16 + k], wi, acc);
            float t2 = wr * cx - wi * sx; wi = wr * sx + wi * cx; wr = t2;
        }
        float val = acc * (1.f / 64.f);
        int idx = y * 64 + x;
        float pre = val + phb[mo + idx];
        float hh = (pre > 0.f) ? 1.0507009873554805f * pre
                               : 1.7580993408473766f * (__expf(pre) - 1.f);
        float z = zb[mo + idx];
        float hn = fmaf(z, hh - hb[mo + idx], hb[mo + idx]);
        hb[mo + idx] = hn;
        hv[j] = hn;
    }
    __syncthreads();
    float* su = smem;
    #pragma unroll
    for (int j = 0; j < 8; j++) {
        int y = ybase + 8 * j;
        su[y * 65 + x] = hv[j];
    }
    __syncthreads();
    dft_stages_512(su, smem + 4160, smem + 5184, Uh + (size_t)map * UMAP);
}

extern "C" void kernel_launch(void* const* d_in, const int* in_sizes, int n_in,
                              void* d_out, int out_size, void* d_ws, size_t ws_size,
                              hipStream_t stream)
{
    (void)in_sizes; (void)n_in; (void)out_size; (void)ws_size;
    const float* x   = (const float*)d_in[0];
    const float* sw1 = (const float*)d_in[1];
    const float* sw2 = (const float*)d_in[2];
    const float* skw = (const float*)d_in[3];
    const float* gb  = (const float*)d_in[4];
    const float* bh  = (const float*)d_in[5];
    float* ws    = (float*)d_ws;
    float* Uxall = ws + OFF_UXALL;
    float* Uh    = ws + OFF_UH;
    float* Urh   = ws + OFF_URH;
    float* Sx    = ws + OFF_SX;
    float* Sp    = ws + OFF_SPART;
    float* hb    = ws + OFF_H;
    float* zb    = ws + OFF_Z;
    float* rhb   = ws + OFF_RH;
    float* phb   = ws + OFF_PH;

    k_init<<<1280, 256, 0, stream>>>(hb, Uh, bh);
    k_dft_x<<<2048, 256, 0, stream>>>(x, Uxall);
    k_mix_x<<<768, 512, 0, stream>>>(Uxall, sw1, sw2, Sx);
    for (int t = 0; t < TT_; t++) {
        const float* xt = x + (size_t)t * CC_ * HW;
        k_front_zr<<<1024, 256, 0, stream>>>(Uh, xt, hb, sw1, sw2, skw, gb,
                                             Sp, zb, rhb);
        k_back_zr<<<512, 512, 0, stream>>>(Sp, Sx, t, zb, rhb, hb, Urh);
        k_front_h<<<512, 256, 0, stream>>>(Urh, xt, rhb, sw1, sw2, skw, gb,
                                           Sp, phb);
        k_back_h<<<256, 512, 0, stream>>>(Sp, Sx, t, zb, phb, hb, Uh);
    }
    hipMemcpyAsync(d_out, hb, (size_t)BB_ * CC_ * HW * sizeof(float),
                   hipMemcpyDeviceToDevice, stream);
}

// Round 4
// 748.359 us; speedup vs baseline: 1.1666x; 1.0520x over previous
//
#include <hip/hip_runtime.h>

#define BB_ 4
#define TT_ 8
#define CC_ 64
#define HW 4096
#define UMAP 1024      // floats per (b,c) spectrum map: 32 ky * 16 kx * 2
#define STEP 0.09817477042468103f   // 2*pi/64

// ws float offsets
#define OFF_UXALL 0                                     // 8*256*1024
#define OFF_UH    (OFF_UXALL + TT_*256*UMAP)            // 256*1024
#define OFF_URH   (OFF_UH + 256*UMAP)                   // 256*1024
#define OFF_SX    (OFF_URH + 256*UMAP)                  // 3 slots * 8 t * 256 maps * 1024
#define OFF_SPART (OFF_SX + 3*TT_*256*UMAP)             // 2 slots * 8 ic * 256 maps * 1024
#define OFF_H     (OFF_SPART + 2*8*256*UMAP)
#define OFF_Z     (OFF_H + BB_*CC_*HW)
#define OFF_RH    (OFF_Z + BB_*CC_*HW)
#define OFF_PH    (OFF_RH + BB_*CC_*HW)

// ---------------- init: h = bias, Uh = spectrum of constant map ----------------
__global__ __launch_bounds__(256) void k_init(float* __restrict__ hb,
                                              float* __restrict__ Uh,
                                              const float* __restrict__ bias_h) {
    float v = bias_h[0];
    int blk = blockIdx.x;
    if (blk < 1024) {
        int idx = (blk * 256 + threadIdx.x) * 4;
        *(float4*)(hb + idx) = make_float4(v, v, v, v);
    } else {
        // spectrum of constant v map: only (ky=0,kx=0) = 4096*v/64 = 64*v
        int map = blk - 1024;
        float4 z = make_float4(0.f, 0.f, 0.f, 0.f);
        if (threadIdx.x == 0) z.x = 64.f * v;
        *(float4*)(Uh + (size_t)map * UMAP + threadIdx.x * 4) = z;
    }
}

// ---------------- forward partial DFT stages, 256-thread variant ----------------
__device__ __forceinline__ void dft_stages(const float* __restrict__ su,
                                           float* __restrict__ FxR, float* __restrict__ FxI,
                                           float* __restrict__ dst) {
    int tid = threadIdx.x;
    int kx = tid & 15, yb = tid >> 4;
    float stc, sts;
    __sincosf(-STEP * (float)kx, &sts, &stc);
    float wr = 1.f, wi = 0.f;
    float aR[4] = {0, 0, 0, 0}, aI[4] = {0, 0, 0, 0};
    for (int x = 0; x < 64; x++) {
        #pragma unroll
        for (int j = 0; j < 4; j++) {
            float v = su[(yb + 16 * j) * 65 + x];
            aR[j] = fmaf(v, wr, aR[j]);
            aI[j] = fmaf(v, wi, aI[j]);
        }
        float t = wr * stc - wi * sts;
        wi = wr * sts + wi * stc;
        wr = t;
    }
    #pragma unroll
    for (int j = 0; j < 4; j++) {
        FxR[(yb + 16 * j) * 16 + kx] = aR[j];
        FxI[(yb + 16 * j) * 16 + kx] = aI[j];
    }
    __syncthreads();
    int kb = tid >> 4;
    float c0, s0, c1, s1;
    __sincosf(-STEP * (float)kb, &s0, &c0);
    __sincosf(-STEP * (float)(kb + 48), &s1, &c1);
    float w0r = 1, w0i = 0, w1r = 1, w1i = 0;
    float A0r = 0, A0i = 0, A1r = 0, A1i = 0;
    for (int y = 0; y < 64; y++) {
        float Fr = FxR[y * 16 + kx], Fi = FxI[y * 16 + kx];
        A0r = fmaf(Fr, w0r, A0r); A0r = fmaf(-Fi, w0i, A0r);
        A0i = fmaf(Fr, w0i, A0i); A0i = fmaf(Fi, w0r, A0i);
        A1r = fmaf(Fr, w1r, A1r); A1r = fmaf(-Fi, w1i, A1r);
        A1i = fmaf(Fr, w1i, A1i); A1i = fmaf(Fi, w1r, A1i);
        float t0 = w0r * c0 - w0i * s0; w0i = w0r * s0 + w0i * c0; w0r = t0;
        float t1 = w1r * c1 - w1i * s1; w1i = w1r * s1 + w1i * c1; w1r = t1;
    }
    const float sc = 1.f / 64.f;
    float2* d2 = (float2*)dst;
    d2[kb * 16 + kx]        = make_float2(A0r * sc, A0i * sc);
    d2[(kb + 16) * 16 + kx] = make_float2(A1r * sc, A1i * sc);
}

// ---------------- forward DFT stages, 512-thread variant ------------------------
__device__ __forceinline__ void dft_stages_512(const float* __restrict__ su,
                                               float* __restrict__ FxR, float* __restrict__ FxI,
                                               float* __restrict__ dst) {
    int tid = threadIdx.x;
    int kx = tid & 15, yb = tid >> 4;            // yb 0..31
    float stc, sts;
    __sincosf(-STEP * (float)kx, &sts, &stc);
    float wr = 1.f, wi = 0.f;
    float aR[2] = {0, 0}, aI[2] = {0, 0};
    for (int x = 0; x < 64; x++) {
        #pragma unroll
        for (int j = 0; j < 2; j++) {
            float v = su[(yb + 32 * j) * 65 + x];
            aR[j] = fmaf(v, wr, aR[j]);
            aI[j] = fmaf(v, wi, aI[j]);
        }
        float t = wr * stc - wi * sts;
        wi = wr * sts + wi * stc;
        wr = t;
    }
    #pragma unroll
    for (int j = 0; j < 2; j++) {
        FxR[(yb + 32 * j) * 16 + kx] = aR[j];
        FxI[(yb + 32 * j) * 16 + kx] = aI[j];
    }
    __syncthreads();
    int kb = tid >> 4;                           // 0..31 = output row
    int ky = (kb < 16) ? kb : kb + 32;           // rows 16..31 hold ky 48..63
    float c0, s0;
    __sincosf(-STEP * (float)ky, &s0, &c0);
    float w0r = 1, w0i = 0, A0r = 0, A0i = 0;
    for (int y = 0; y < 64; y++) {
        float Fr = FxR[y * 16 + kx], Fi = FxI[y * 16 + kx];
        A0r = fmaf(Fr, w0r, A0r); A0r = fmaf(-Fi, w0i, A0r);
        A0i = fmaf(Fr, w0i, A0i); A0i = fmaf(Fi, w0r, A0i);
        float t0 = w0r * c0 - w0i * s0; w0i = w0r * s0 + w0i * c0; w0r = t0;
    }
    const float sc = 1.f / 64.f;
    ((float2*)dst)[kb * 16 + kx] = make_float2(A0r * sc, A0i * sc);
}

// ---------------- batched DFT of all x_t maps (once per launch) ----------------
__global__ __launch_bounds__(256) void k_dft_x(const float* __restrict__ x,
                                               float* __restrict__ Uxall) {
    __shared__ float su[64 * 65];
    __shared__ float FxR[1024], FxI[1024];
    int blk = blockIdx.x;
    int t = blk >> 8, map = blk & 255;
    int b = map >> 6, c = map & 63;
    const float* src = x + (((size_t)b * TT_ + t) * CC_ + c) * HW;
    int tid = threadIdx.x;
    #pragma unroll
    for (int k = 0; k < 4; k++) {
        int off = k * 1024 + tid * 4;
        float4 v = *(const float4*)(src + off);
        int y = off >> 6, xx = off & 63;
        su[y * 65 + xx + 0] = v.x; su[y * 65 + xx + 1] = v.y;
        su[y * 65 + xx + 2] = v.z; su[y * 65 + xx + 3] = v.w;
    }
    __syncthreads();
    dft_stages(su, FxR, FxI, Uxall + ((size_t)t * 256 + map) * UMAP);
}

// ---------------- mix accumulation core (h-side, unchanged) ---------------------
__device__ __forceinline__ void mix_load(const float2* __restrict__ W2,
                                         const float2* __restrict__ U2, int i,
                                         float2 w[4], float2 u[4]) {
    const float2* wp = W2 + (size_t)i * 16384;
    const float2* up = U2 + (size_t)i * 512;
    w[0] = wp[0]; w[1] = wp[256]; w[2] = wp[512]; w[3] = wp[768];
    u[0] = up[0]; u[1] = up[32768]; u[2] = up[65536]; u[3] = up[98304];
}

__device__ __forceinline__ void mix_fma(const float2 w[4], const float2 u[4],
                                        float aR[4][4], float aI[4][4]) {
    #pragma unroll
    for (int oo = 0; oo < 4; oo++)
        #pragma unroll
        for (int bb = 0; bb < 4; bb++) {
            aR[oo][bb] = fmaf(u[bb].x, w[oo].x, aR[oo][bb]);
            aR[oo][bb] = fmaf(-u[bb].y, w[oo].y, aR[oo][bb]);
            aI[oo][bb] = fmaf(u[bb].x, w[oo].y, aI[oo][bb]);
            aI[oo][bb] = fmaf(u[bb].y, w[oo].x, aI[oo][bb]);
        }
}

// depth-3 pipeline (used by per-step h-side mixes, niter=8)
__device__ __forceinline__ void mix_accum(const float2* __restrict__ W2,
                                          const float2* __restrict__ U2,
                                          int niter, float aR[4][4], float aI[4][4])
{
    float2 wA[4], uA[4], wB[4], uB[4], wN[4], uN[4];
    mix_load(W2, U2, 0, wA, uA);
    mix_load(W2, U2, 1, wB, uB);
    for (int i = 0; i + 2 < niter; i += 2) {
        mix_load(W2, U2, i + 2, wN, uN);
        mix_fma(wA, uA, aR, aI);
        #pragma unroll
        for (int k = 0; k < 4; k++) { wA[k] = wN[k]; uA[k] = uN[k]; }
        mix_load(W2, U2, i + 3, wN, uN);
        mix_fma(wB, uB, aR, aI);
        #pragma unroll
        for (int k = 0; k < 4; k++) { wB[k] = wN[k]; uB[k] = uN[k]; }
    }
    mix_fma(wA, uA, aR, aI);
    mix_fma(wB, uB, aR, aI);
}

// ---------------- upfront: all x-side mixes, LDS double-buffer pipeline ---------
// v5: same MLP theory as v4 (k_mix_x latency-bound: 3 rounds flat at 76us with
// VALU 17%, HBM 14%, LDS 0, occ 35% -- nothing saturated), but implemented in
// plain HIP after v4's global_load_lds+inline-asm build took the container down.
// Pattern: global -> regs (5 float4/thread, full 128B lines) -> ds_write ->
// barrier -> compute. The prefetch for chunk c+1 is issued BEFORE the barrier
// and consumed only at the NEXT iteration's ds_write, so ~80B/lane stays in
// flight across the whole 256-fma compute phase; __syncthreads structurally
// prevents the compiler from collapsing the overlap (round-1 lesson).
// Block = (li,half,op,mq): o-tile 8, m-tile 16, all 32 tb, K chunked by 4.
// Grid 768 x 256 thr. LDS 40KB (4 blocks/CU cap). W staged once device-wide.
__global__ __launch_bounds__(256, 4) void k_mix_x(
    const float* __restrict__ Uxall,
    const float* __restrict__ sw1, const float* __restrict__ sw2,
    float* __restrict__ Sx)
{
    __shared__ float4 Wt4[2][256];    // [buf][(ii*8+oo)*4 + wl]   8 KB
    __shared__ float4 Ut4[2][1024];   // [buf][ii*256 + tb*8 + wl] 32 KB
    int blk = blockIdx.x;
    int mq = blk & 15;
    int op = (blk >> 4) & 7;
    int half = (blk >> 7) & 1;
    int li = blk >> 8;          // 0,1,2 -> layers 0,2,4
    int l = li * 2;
    int tid = threadIdx.x;
    int m0 = mq * 16;
    int o0 = op * 8;
    const float2* wsrc = (const float2*)(half ? sw2 : sw1);
    const float2* usrc = (const float2*)Uxall;

    // staging addresses: thread -> one 16B part of a 128B row
    int wl = tid & 7;                       // 16B lane-part within a 128B row
    int wrow = tid >> 3;                    // 32 rows
    int wii = wrow >> 3, woo = wrow & 7;    // W rows: 4i x 8o
    const float4* wg4 = (const float4*)(wsrc
        + (((size_t)(l * 64 + wii) * 64) + o0 + woo) * 256 + m0) + wl;
    int ut_ = wrow >> 2, ub_ = wrow & 3;    // U rows: 8t x 4b
    const float4* ug4 = (const float4*)(usrc
        + (size_t)ut_ * 131072 + (size_t)ub_ * 32768 + half * 256 + m0) + wl;

    int mt = tid & 15, pp = tid >> 4;       // compute mapping: mode, tb-pair
    float aR[8][2], aI[8][2];
    #pragma unroll
    for (int oo = 0; oo < 8; oo++) {
        aR[oo][0] = 0.f; aR[oo][1] = 0.f;
        aI[oo][0] = 0.f; aI[oo][1] = 0.f;
    }

    // prologue: chunk 0 -> regs
    float4 wv  = wg4[0];
    float4 uv0 = ug4[0];
    float4 uv1 = ug4[256];
    float4 uv2 = ug4[512];
    float4 uv3 = ug4[768];

    for (int c = 0; c < 16; ++c) {
        int cb = c & 1;
        // stage current chunk from regs into LDS
        Wt4[cb][tid] = wv;
        Ut4[cb][tid] = uv0;
        Ut4[cb][256 + tid] = uv1;
        Ut4[cb][512 + tid] = uv2;
        Ut4[cb][768 + tid] = uv3;
        // issue next chunk's loads; consumed at next iteration's ds_write,
        // so they stay in flight across the barrier + compute below.
        if (c < 15) {
            size_t ib = (size_t)(c + 1) * 4;
            wv  = wg4[ib * 8192];
            uv0 = ug4[ib * 256];
            uv1 = ug4[(ib + 1) * 256];
            uv2 = ug4[(ib + 2) * 256];
            uv3 = ug4[(ib + 3) * 256];
        }
        __syncthreads();
        const float2* Wl = (const float2*)Wt4[cb];
        const float2* Ul = (const float2*)Ut4[cb];
        #pragma unroll
        for (int ii = 0; ii < 4; ii++) {
            float2 u0 = Ul[(ii * 32 + 2 * pp) * 16 + mt];
            float2 u1 = Ul[(ii * 32 + 2 * pp + 1) * 16 + mt];
            #pragma unroll
            for (int oo = 0; oo < 8; oo++) {
                float2 w = Wl[(ii * 8 + oo) * 16 + mt];
                aR[oo][0] = fmaf(u0.x, w.x, aR[oo][0]);
                aR[oo][0] = fmaf(-u0.y, w.y, aR[oo][0]);
                aI[oo][0] = fmaf(u0.x, w.y, aI[oo][0]);
                aI[oo][0] = fmaf(u0.y, w.x, aI[oo][0]);
                aR[oo][1] = fmaf(u1.x, w.x, aR[oo][1]);
                aR[oo][1] = fmaf(-u1.y, w.y, aR[oo][1]);
                aI[oo][1] = fmaf(u1.x, w.y, aI[oo][1]);
                aI[oo][1] = fmaf(u1.y, w.x, aI[oo][1]);
            }
        }
        __syncthreads();
    }

    // epilogue: write Sx (same layout as rounds 0-2)
    float2* S2 = (float2*)Sx;
    #pragma unroll
    for (int oo = 0; oo < 8; oo++)
        #pragma unroll
        for (int j = 0; j < 2; j++) {
            int tb = 2 * pp + j;
            int t = tb >> 2, b = tb & 3;
            S2[((size_t)(li * 8 + t) * 256 + b * 64 + o0 + oo) * 512
               + half * 256 + m0 + mt] = make_float2(aR[oo][j], aI[oo][j]);
        }
}

// ---------------- per-step h-side mix body --------------------------------------
// blk bits: [g][half][ic(8)][og(16)]; 8 i per block.
// Spart layout: [(g*8+ic)*256 + b*64+o][UMAP]
__device__ __forceinline__ void mix_body_h(int blk, int l0, int l1,
    const float* __restrict__ U,
    const float* __restrict__ sw1, const float* __restrict__ sw2,
    float* __restrict__ Spart)
{
    int og = blk & 15;
    int ic = (blk >> 4) & 7;
    int half = (blk >> 7) & 1;
    int g = (blk >> 8) & 1;
    int m = threadIdx.x;
    int o0 = og * 4, ib = ic * 8;
    int l = g ? l1 : l0;
    const float2* wt = (const float2*)(half ? sw2 : sw1);
    const float2* W2 = wt + (((size_t)l * 64 + ib) * 64 + o0) * 256 + m;
    const float2* U2 = (const float2*)U + (size_t)ib * 512 + half * 256 + m;
    float aR[4][4], aI[4][4];
    #pragma unroll
    for (int oo = 0; oo < 4; oo++)
        #pragma unroll
        for (int b = 0; b < 4; b++) { aR[oo][b] = 0.f; aI[oo][b] = 0.f; }
    mix_accum(W2, U2, 8, aR, aI);
    float2* S2 = (float2*)Spart;
    #pragma unroll
    for (int oo = 0; oo < 4; oo++)
        #pragma unroll
        for (int b = 0; b < 4; b++)
            S2[((size_t)(g * 8 + ic) * 256 + b * 64 + o0 + oo) * 512 + half * 256 + m]
                = make_float2(aR[oo][b], aI[oo][b]);
}

// ---------------- 1x1-conv skip: register-tiled GEMM ----------------------------
// thread = 4o x 4px tile, block = 32o x 128px for one (gate, b, oh).
// rr bits: [b(2)][oh(1)][pxc(5)] = 256 blocks per gate.
__device__ __forceinline__ void fma16(const float4 w, const float4 u, float acc[4][4]) {
    acc[0][0] = fmaf(u.x, w.x, acc[0][0]); acc[0][1] = fmaf(u.y, w.x, acc[0][1]);
    acc[0][2] = fmaf(u.z, w.x, acc[0][2]); acc[0][3] = fmaf(u.w, w.x, acc[0][3]);
    acc[1][0] = fmaf(u.x, w.y, acc[1][0]); acc[1][1] = fmaf(u.y, w.y, acc[1][1]);
    acc[1][2] = fmaf(u.z, w.y, acc[1][2]); acc[1][3] = fmaf(u.w, w.y, acc[1][3]);
    acc[2][0] = fmaf(u.x, w.z, acc[2][0]); acc[2][1] = fmaf(u.y, w.z, acc[2][1]);
    acc[2][2] = fmaf(u.z, w.z, acc[2][2]); acc[2][3] = fmaf(u.w, w.z, acc[2][3]);
    acc[3][0] = fmaf(u.x, w.w, acc[3][0]); acc[3][1] = fmaf(u.y, w.w, acc[3][1]);
    acc[3][2] = fmaf(u.z, w.w, acc[3][2]); acc[3][3] = fmaf(u.w, w.w, acc[3][3]);
}

__device__ __forceinline__ void skip_gemm(int rr, float* __restrict__ sW,
    const float* __restrict__ uA, long long bsA,
    const float* __restrict__ uB, long long bsB,
    const float* __restrict__ skw, int lA, int lB, float gb,
    float* __restrict__ out)
{
    int pxc = rr & 31, oh = (rr >> 5) & 1, b = rr >> 6;
    int tid = threadIdx.x;
    int ot = tid & 7, pt = tid >> 3;       // 8 o-tiles x 4o, 32 px-tiles x 4px
    // stage sW[k=p*64+i][oc] (k=128, oc=32): 16 KB, fully coalesced
    #pragma unroll
    for (int n = 0; n < 4; n++) {
        int idx = n * 1024 + tid * 4;
        int k = idx >> 5, oc = idx & 31;
        int p = k >> 6, i = k & 63;
        *(float4*)(sW + idx) =
            *(const float4*)(skw + (p ? lB : lA) * 4096 + i * 64 + oh * 32 + oc);
    }
    __syncthreads();
    float acc[4][4];
    #pragma unroll
    for (int oo = 0; oo < 4; oo++)
        #pragma unroll
        for (int q = 0; q < 4; q++) acc[oo][q] = 0.f;
    const float* pa = uA + (long long)b * bsA + pxc * 128 + pt * 4;
    const float* pb = uB + (long long)b * bsB + pxc * 128 + pt * 4;
    const float4* sW4 = (const float4*)sW;   // [128][8] float4
    #pragma unroll 4
    for (int i = 0; i < 64; i++) {
        float4 ua = *(const float4*)(pa + (size_t)i * HW);
        float4 wa = sW4[i * 8 + ot];
        fma16(wa, ua, acc);
        float4 ub = *(const float4*)(pb + (size_t)i * HW);
        float4 wb = sW4[(64 + i) * 8 + ot];
        fma16(wb, ub, acc);
    }
    float* op = out + ((long long)(b * 64 + oh * 32 + ot * 4)) * HW + pxc * 128 + pt * 4;
    #pragma unroll
    for (int oo = 0; oo < 4; oo++) {
        float4 r = make_float4(acc[oo][0] + gb, acc[oo][1] + gb,
                               acc[oo][2] + gb, acc[oo][3] + gb);
        *(float4*)(op + (size_t)oo * HW) = r;
    }
}

// ---------------- fused front kernels: h-side mix + skip ------------------------
__global__ __launch_bounds__(256) void k_front_zr(
    const float* __restrict__ Uh,
    const float* __restrict__ xt, const float* __restrict__ hb,
    const float* __restrict__ sw1, const float* __restrict__ sw2,
    const float* __restrict__ skw, const float* __restrict__ gate_b,
    float* __restrict__ Spart, float* __restrict__ zb, float* __restrict__ rhb)
{
    __shared__ float smem[4096];
    int blk = blockIdx.x;
    if (blk < 512) {
        mix_body_h(blk, 1, 3, Uh, sw1, sw2, Spart);
    } else {
        int r = blk - 512;
        int g = r >> 8;
        skip_gemm(r & 255, smem,
                  xt, (long long)TT_ * CC_ * HW, hb, (long long)CC_ * HW,
                  skw, g ? 2 : 0, g ? 3 : 1, gate_b[g], g ? rhb : zb);
    }
}

__global__ __launch_bounds__(256) void k_front_h(
    const float* __restrict__ Urh,
    const float* __restrict__ xt, const float* __restrict__ rhb,
    const float* __restrict__ sw1, const float* __restrict__ sw2,
    const float* __restrict__ skw, const float* __restrict__ gate_b,
    float* __restrict__ Spart, float* __restrict__ phb)
{
    __shared__ float smem[4096];
    int blk = blockIdx.x;
    if (blk < 256) {
        mix_body_h(blk, 5, 5, Urh, sw1, sw2, Spart);
    } else {
        int r = blk - 256;
        skip_gemm(r, smem,
                  xt, (long long)TT_ * CC_ * HW, rhb, (long long)CC_ * HW,
                  skw, 4, 5, gate_b[2], phb);
    }
}

// ---------------- inverse DFT stage 1, 512-thread variant -----------------------
__device__ __forceinline__ void idft_stage1_512(const float* __restrict__ SR,
                                                const float* __restrict__ SI,
                                                float* __restrict__ GR, float* __restrict__ GI)
{
    int tid = threadIdx.x;
    int kx = tid & 15, yb = tid >> 4;        // yb 0..31
    #pragma unroll
    for (int j = 0; j < 2; j++) {
        int y = yb + 32 * j;
        float stc, sts;
        __sincosf(STEP * (float)y, &sts, &stc);
        float ar = 0.f, ai = 0.f;
        float wr = 1.f, wi = 0.f;
        for (int k = 0; k < 16; k++) {
            float sr_ = SR[k * 16 + kx], si_ = SI[k * 16 + kx];
            ar = fmaf(sr_, wr, ar); ar = fmaf(-si_, wi, ar);
            ai = fmaf(sr_, wi, ai); ai = fmaf(si_, wr, ai);
            float t = wr * stc - wi * sts; wi = wr * sts + wi * stc; wr = t;
        }
        int q = (3 * y) & 3;
        float w2r = (q == 0) ? 1.f : ((q == 2) ? -1.f : 0.f);
        float w2i = (q == 1) ? 1.f : ((q == 3) ? -1.f : 0.f);
        for (int k = 16; k < 32; k++) {
            float sr_ = SR[k * 16 + kx], si_ = SI[k * 16 + kx];
            ar = fmaf(sr_, w2r, ar); ar = fmaf(-si_, w2i, ar);
            ai = fmaf(sr_, w2i, ai); ai = fmaf(si_, w2r, ai);
            float t = w2r * stc - w2i * sts; w2i = w2r * sts + w2i * stc; w2r = t;
        }
        GR[y * 16 + kx] = ar;
        GI[y * 16 + kx] = ai;
    }
}

// ---------------- back kernel zr (512 thr): idft + gates + fused rh DFT ---------
__global__ __launch_bounds__(512) void k_back_zr(
    const float* __restrict__ Spart, const float* __restrict__ Sx, int t,
    float* __restrict__ zb, float* __restrict__ rhb,
    const float* __restrict__ hb, float* __restrict__ Urh)
{
    __shared__ float smem[6208];
    float* SR = smem;          // 512
    float* SI = smem + 512;    // 512
    float* GR = smem + 1024;   // 1024
    float* GI = smem + 2048;   // 1024
    int g = blockIdx.x >> 8;
    int map = blockIdx.x & 255;
    int tid = threadIdx.x;
    {
        float2 v = ((const float2*)Sx)[((size_t)(g * 8 + t) * 256 + map) * 512 + tid];
        float sr = v.x, si = v.y;
        const float2* base = (const float2*)Spart;
        #pragma unroll
        for (int ic = 0; ic < 8; ic++) {
            float2 p = base[((size_t)(g * 8 + ic) * 256 + map) * 512 + tid];
            sr += p.x; si += p.y;
        }
        SR[tid] = sr; SI[tid] = si;
    }
    __syncthreads();
    idft_stage1_512(SR, SI, GR, GI);
    __syncthreads();
    int x = tid & 63, ybase = tid >> 6;      // ybase 0..7
    float cx, sx;
    __sincosf(STEP * (float)x, &sx, &cx);
    size_t mo = (size_t)map * HW;
    float rhv[8];
    #pragma unroll
    for (int j = 0; j < 8; j++) {
        int y = ybase + 8 * j;
        float acc = GR[y * 16];
        float wr = cx, wi = sx;
        #pragma unroll
        for (int k = 1; k < 16; k++) {
            acc = fmaf(2.f * GR[y * 16 + k], wr, acc);
            acc = fmaf(-2.f * GI[y * 16 + k], wi, acc);
            float t2 = wr * cx - wi * sx; wi = wr * sx + wi * cx; wr = t2;
        }
        float val = acc * (1.f / 64.f);
        int idx = y * 64 + x;
        if (g == 0) {
            float pre = val + zb[mo + idx];
            zb[mo + idx] = 1.f / (1.f + __expf(-pre));
        } else {
            float pre = val + rhb[mo + idx];
            float rr = 1.f / (1.f + __expf(-pre));
            float rh = rr * hb[mo + idx];
            rhb[mo + idx] = rh;
            rhv[j] = rh;
        }
    }
    if (g == 0) return;
    __syncthreads();
    float* su = smem;
    #pragma unroll
    for (int j = 0; j < 8; j++) {
        int y = ybase + 8 * j;
        su[y * 65 + x] = rhv[j];
    }
    __syncthreads();
    dft_stages_512(su, smem + 4160, smem + 5184, Urh + (size_t)map * UMAP);
}

// ---------------- back kernel h (512 thr): idft + GRU update + fused h DFT ------
__global__ __launch_bounds__(512) void k_back_h(
    const float* __restrict__ Spart, const float* __restrict__ Sx, int t,
    const float* __restrict__ zb, const float* __restrict__ phb,
    float* __restrict__ hb, float* __restrict__ Uh)
{
    __shared__ float smem[6208];
    float* SR = smem;
    float* SI = smem + 512;
    float* GR = smem + 1024;
    float* GI = smem + 2048;
    int map = blockIdx.x & 255;
    int tid = threadIdx.x;
    {
        float2 v = ((const float2*)Sx)[((size_t)(2 * 8 + t) * 256 + map) * 512 + tid];
        float sr = v.x, si = v.y;
        const float2* base = (const float2*)Spart;
        #pragma unroll
        for (int ic = 0; ic < 8; ic++) {
            float2 p = base[((size_t)ic * 256 + map) * 512 + tid];
            sr += p.x; si += p.y;
        }
        SR[tid] = sr; SI[tid] = si;
    }
    __syncthreads();
    idft_stage1_512(SR, SI, GR, GI);
    __syncthreads();
    int x = tid & 63, ybase = tid >> 6;
    float cx, sx;
    __sincosf(STEP * (float)x, &sx, &cx);
    size_t mo = (size_t)map * HW;
    float hv[8];
    #pragma unroll
    for (int j = 0; j < 8; j++) {
        int y = ybase + 8 * j;
        float acc = GR[y * 16];
        float wr = cx, wi = sx;
        #pragma unroll
        for (int k = 1; k < 16; k++) {
            acc = fmaf(2.f * GR[y * 16 + k], wr, acc);
            acc = fmaf(-2.f * GI[y * 16 + k], wi, acc);
            float t2 = wr * cx - wi * sx; wi = wr * sx + wi * cx; wr = t2;
        }
        float val = acc * (1.f / 64.f);
        int idx = y * 64 + x;
        float pre = val + phb[mo + idx];
        float hh = (pre > 0.f) ? 1.0507009873554805f * pre
                               : 1.7580993408473766f * (__expf(pre) - 1.f);
        float z = zb[mo + idx];
        float hn = fmaf(z, hh - hb[mo + idx], hb[mo + idx]);
        hb[mo + idx] = hn;
        hv[j] = hn;
    }
    __syncthreads();
    float* su = smem;
    #pragma unroll
    for (int j = 0; j < 8; j++) {
        int y = ybase + 8 * j;
        su[y * 65 + x] = hv[j];
    }
    __syncthreads();
    dft_stages_512(su, smem + 4160, smem + 5184, Uh + (size_t)map * UMAP);
}

extern "C" void kernel_launch(void* const* d_in, const int* in_sizes, int n_in,
                              void* d_out, int out_size, void* d_ws, size_t ws_size,
                              hipStream_t stream)
{
    (void)in_sizes; (void)n_in; (void)out_size; (void)ws_size;
    const float* x   = (const float*)d_in[0];
    const float* sw1 = (const float*)d_in[1];
    const float* sw2 = (const float*)d_in[2];
    const float* skw = (const float*)d_in[3];
    const float* gb  = (const float*)d_in[4];
    const float* bh  = (const float*)d_in[5];
    float* ws    = (float*)d_ws;
    float* Uxall = ws + OFF_UXALL;
    float* Uh    = ws + OFF_UH;
    float* Urh   = ws + OFF_URH;
    float* Sx    = ws + OFF_SX;
    float* Sp    = ws + OFF_SPART;
    float* hb    = ws + OFF_H;
    float* zb    = ws + OFF_Z;
    float* rhb   = ws + OFF_RH;
    float* phb   = ws + OFF_PH;

    k_init<<<1280, 256, 0, stream>>>(hb, Uh, bh);
    k_dft_x<<<2048, 256, 0, stream>>>(x, Uxall);
    k_mix_x<<<768, 256, 0, stream>>>(Uxall, sw1, sw2, Sx);
    for (int t = 0; t < TT_; t++) {
        const float* xt = x + (size_t)t * CC_ * HW;
        k_front_zr<<<1024, 256, 0, stream>>>(Uh, xt, hb, sw1, sw2, skw, gb,
                                             Sp, zb, rhb);
        k_back_zr<<<512, 512, 0, stream>>>(Sp, Sx, t, zb, rhb, hb, Urh);
        k_front_h<<<512, 256, 0, stream>>>(Urh, xt, rhb, sw1, sw2, skw, gb,
                                           Sp, phb);
        k_back_h<<<256, 512, 0, stream>>>(Sp, Sx, t, zb, phb, hb, Uh);
    }
    hipMemcpyAsync(d_out, hb, (size_t)BB_ * CC_ * HW * sizeof(float),
                   hipMemcpyDeviceToDevice, stream);
}

// Round 5
// 741.860 us; speedup vs baseline: 1.1768x; 1.0088x over previous
//
#include <hip/hip_runtime.h>

#define BB_ 4
#define TT_ 8
#define CC_ 64
#define HW 4096
#define UMAP 1024      // floats per (b,c) spectrum map: 32 ky * 16 kx * 2
#define STEP 0.09817477042468103f   // 2*pi/64

// ws float offsets
#define OFF_UXALL 0                                     // 8*256*1024
#define OFF_UH    (OFF_UXALL + TT_*256*UMAP)            // 256*1024
#define OFF_URH   (OFF_UH + 256*UMAP)                   // 256*1024
#define OFF_SX    (OFF_URH + 256*UMAP)                  // 3 slots * 8 t * 256 maps * 1024
#define OFF_SPART (OFF_SX + 3*TT_*256*UMAP)             // 2 slots * 8 ic * 256 maps * 1024
#define OFF_H     (OFF_SPART + 2*8*256*UMAP)
#define OFF_Z     (OFF_H + BB_*CC_*HW)
#define OFF_RH    (OFF_Z + BB_*CC_*HW)
#define OFF_PH    (OFF_RH + BB_*CC_*HW)

// ---------------- init: h = bias, Uh = spectrum of constant map ----------------
__global__ __launch_bounds__(256) void k_init(float* __restrict__ hb,
                                              float* __restrict__ Uh,
                                              const float* __restrict__ bias_h) {
    float v = bias_h[0];
    int blk = blockIdx.x;
    if (blk < 1024) {
        int idx = (blk * 256 + threadIdx.x) * 4;
        *(float4*)(hb + idx) = make_float4(v, v, v, v);
    } else {
        // spectrum of constant v map: only (ky=0,kx=0) = 4096*v/64 = 64*v
        int map = blk - 1024;
        float4 z = make_float4(0.f, 0.f, 0.f, 0.f);
        if (threadIdx.x == 0) z.x = 64.f * v;
        *(float4*)(Uh + (size_t)map * UMAP + threadIdx.x * 4) = z;
    }
}

// ---------------- forward partial DFT stages, 256-thread variant ----------------
__device__ __forceinline__ void dft_stages(const float* __restrict__ su,
                                           float* __restrict__ FxR, float* __restrict__ FxI,
                                           float* __restrict__ dst) {
    int tid = threadIdx.x;
    int kx = tid & 15, yb = tid >> 4;
    float stc, sts;
    __sincosf(-STEP * (float)kx, &sts, &stc);
    float wr = 1.f, wi = 0.f;
    float aR[4] = {0, 0, 0, 0}, aI[4] = {0, 0, 0, 0};
    for (int x = 0; x < 64; x++) {
        #pragma unroll
        for (int j = 0; j < 4; j++) {
            float v = su[(yb + 16 * j) * 65 + x];
            aR[j] = fmaf(v, wr, aR[j]);
            aI[j] = fmaf(v, wi, aI[j]);
        }
        float t = wr * stc - wi * sts;
        wi = wr * sts + wi * stc;
        wr = t;
    }
    #pragma unroll
    for (int j = 0; j < 4; j++) {
        FxR[(yb + 16 * j) * 16 + kx] = aR[j];
        FxI[(yb + 16 * j) * 16 + kx] = aI[j];
    }
    __syncthreads();
    int kb = tid >> 4;
    float c0, s0, c1, s1;
    __sincosf(-STEP * (float)kb, &s0, &c0);
    __sincosf(-STEP * (float)(kb + 48), &s1, &c1);
    float w0r = 1, w0i = 0, w1r = 1, w1i = 0;
    float A0r = 0, A0i = 0, A1r = 0, A1i = 0;
    for (int y = 0; y < 64; y++) {
        float Fr = FxR[y * 16 + kx], Fi = FxI[y * 16 + kx];
        A0r = fmaf(Fr, w0r, A0r); A0r = fmaf(-Fi, w0i, A0r);
        A0i = fmaf(Fr, w0i, A0i); A0i = fmaf(Fi, w0r, A0i);
        A1r = fmaf(Fr, w1r, A1r); A1r = fmaf(-Fi, w1i, A1r);
        A1i = fmaf(Fr, w1i, A1i); A1i = fmaf(Fi, w1r, A1i);
        float t0 = w0r * c0 - w0i * s0; w0i = w0r * s0 + w0i * c0; w0r = t0;
        float t1 = w1r * c1 - w1i * s1; w1i = w1r * s1 + w1i * c1; w1r = t1;
    }
    const float sc = 1.f / 64.f;
    float2* d2 = (float2*)dst;
    d2[kb * 16 + kx]        = make_float2(A0r * sc, A0i * sc);
    d2[(kb + 16) * 16 + kx] = make_float2(A1r * sc, A1i * sc);
}

// ---------------- forward DFT stages, 512-thread variant ------------------------
__device__ __forceinline__ void dft_stages_512(const float* __restrict__ su,
                                               float* __restrict__ FxR, float* __restrict__ FxI,
                                               float* __restrict__ dst) {
    int tid = threadIdx.x;
    int kx = tid & 15, yb = tid >> 4;            // yb 0..31
    float stc, sts;
    __sincosf(-STEP * (float)kx, &sts, &stc);
    float wr = 1.f, wi = 0.f;
    float aR[2] = {0, 0}, aI[2] = {0, 0};
    for (int x = 0; x < 64; x++) {
        #pragma unroll
        for (int j = 0; j < 2; j++) {
            float v = su[(yb + 32 * j) * 65 + x];
            aR[j] = fmaf(v, wr, aR[j]);
            aI[j] = fmaf(v, wi, aI[j]);
        }
        float t = wr * stc - wi * sts;
        wi = wr * sts + wi * stc;
        wr = t;
    }
    #pragma unroll
    for (int j = 0; j < 2; j++) {
        FxR[(yb + 32 * j) * 16 + kx] = aR[j];
        FxI[(yb + 32 * j) * 16 + kx] = aI[j];
    }
    __syncthreads();
    int kb = tid >> 4;                           // 0..31 = output row
    int ky = (kb < 16) ? kb : kb + 32;           // rows 16..31 hold ky 48..63
    float c0, s0;
    __sincosf(-STEP * (float)ky, &s0, &c0);
    float w0r = 1, w0i = 0, A0r = 0, A0i = 0;
    for (int y = 0; y < 64; y++) {
        float Fr = FxR[y * 16 + kx], Fi = FxI[y * 16 + kx];
        A0r = fmaf(Fr, w0r, A0r); A0r = fmaf(-Fi, w0i, A0r);
        A0i = fmaf(Fr, w0i, A0i); A0i = fmaf(Fi, w0r, A0i);
        float t0 = w0r * c0 - w0i * s0; w0i = w0r * s0 + w0i * c0; w0r = t0;
    }
    const float sc = 1.f / 64.f;
    ((float2*)dst)[kb * 16 + kx] = make_float2(A0r * sc, A0i * sc);
}

// ---------------- batched DFT of all x_t maps (once per launch) ----------------
__global__ __launch_bounds__(256) void k_dft_x(const float* __restrict__ x,
                                               float* __restrict__ Uxall) {
    __shared__ float su[64 * 65];
    __shared__ float FxR[1024], FxI[1024];
    int blk = blockIdx.x;
    int t = blk >> 8, map = blk & 255;
    int b = map >> 6, c = map & 63;
    const float* src = x + (((size_t)b * TT_ + t) * CC_ + c) * HW;
    int tid = threadIdx.x;
    #pragma unroll
    for (int k = 0; k < 4; k++) {
        int off = k * 1024 + tid * 4;
        float4 v = *(const float4*)(src + off);
        int y = off >> 6, xx = off & 63;
        su[y * 65 + xx + 0] = v.x; su[y * 65 + xx + 1] = v.y;
        su[y * 65 + xx + 2] = v.z; su[y * 65 + xx + 3] = v.w;
    }
    __syncthreads();
    dft_stages(su, FxR, FxI, Uxall + ((size_t)t * 256 + map) * UMAP);
}

// ---------------- mix accumulation core (h-side, unchanged) ---------------------
__device__ __forceinline__ void mix_load(const float2* __restrict__ W2,
                                         const float2* __restrict__ U2, int i,
                                         float2 w[4], float2 u[4]) {
    const float2* wp = W2 + (size_t)i * 16384;
    const float2* up = U2 + (size_t)i * 512;
    w[0] = wp[0]; w[1] = wp[256]; w[2] = wp[512]; w[3] = wp[768];
    u[0] = up[0]; u[1] = up[32768]; u[2] = up[65536]; u[3] = up[98304];
}

__device__ __forceinline__ void mix_fma(const float2 w[4], const float2 u[4],
                                        float aR[4][4], float aI[4][4]) {
    #pragma unroll
    for (int oo = 0; oo < 4; oo++)
        #pragma unroll
        for (int bb = 0; bb < 4; bb++) {
            aR[oo][bb] = fmaf(u[bb].x, w[oo].x, aR[oo][bb]);
            aR[oo][bb] = fmaf(-u[bb].y, w[oo].y, aR[oo][bb]);
            aI[oo][bb] = fmaf(u[bb].x, w[oo].y, aI[oo][bb]);
            aI[oo][bb] = fmaf(u[bb].y, w[oo].x, aI[oo][bb]);
        }
}

// depth-3 pipeline (used by per-step h-side mixes, niter=8)
__device__ __forceinline__ void mix_accum(const float2* __restrict__ W2,
                                          const float2* __restrict__ U2,
                                          int niter, float aR[4][4], float aI[4][4])
{
    float2 wA[4], uA[4], wB[4], uB[4], wN[4], uN[4];
    mix_load(W2, U2, 0, wA, uA);
    mix_load(W2, U2, 1, wB, uB);
    for (int i = 0; i + 2 < niter; i += 2) {
        mix_load(W2, U2, i + 2, wN, uN);
        mix_fma(wA, uA, aR, aI);
        #pragma unroll
        for (int k = 0; k < 4; k++) { wA[k] = wN[k]; uA[k] = uN[k]; }
        mix_load(W2, U2, i + 3, wN, uN);
        mix_fma(wB, uB, aR, aI);
        #pragma unroll
        for (int k = 0; k < 4; k++) { wB[k] = wN[k]; uB[k] = uN[k]; }
    }
    mix_fma(wA, uA, aR, aI);
    mix_fma(wB, uB, aR, aI);
}

// ---------------- upfront: all x-side mixes, v6 ---------------------------------
// v5 post-mortem: U staging through LDS was pure overhead (each U element is
// consumed by exactly ONE thread -- zero reuse), while W has 16x reuse across
// pp-lanes. v6: only W in LDS, transposed [ii][m][oo] (pad 10) so a thread's 8
// w-values are 4x b128 instead of 8x b64; U loads go direct global->reg
// (coalesced 128B per 16-lane group, L2-hot); ONE barrier per chunk via true
// W double-buffering. LDS 10.2 KB.
__global__ __launch_bounds__(256, 4) void k_mix_x(
    const float* __restrict__ Uxall,
    const float* __restrict__ sw1, const float* __restrict__ sw2,
    float* __restrict__ Sx)
{
    __shared__ __align__(16) float2 Wl[2][640];   // [buf][(ii*16+m)*10 + oo]
    int blk = blockIdx.x;
    int mq = blk & 15;
    int op = (blk >> 4) & 7;
    int half = (blk >> 7) & 1;
    int li = blk >> 8;          // 0,1,2 -> layers 0,2,4
    int l = li * 2;
    int tid = threadIdx.x;
    int m0 = mq * 16;
    int o0 = op * 8;
    const float2* wsrc = (const float2*)(half ? sw2 : sw1);
    const float2* usrc = (const float2*)Uxall;

    // W staging address: thread -> one 16B part (2 m) of one (ii, oo) row
    int wl = tid & 7;                       // m-part: m = 2*wl, 2*wl+1
    int wrow = tid >> 3;                    // 32 rows = 4 ii x 8 oo
    int wii = wrow >> 3, woo = wrow & 7;
    const float4* wg4 = (const float4*)(wsrc
        + (((size_t)(l * 64 + wii) * 64) + o0 + woo) * 256 + m0) + wl;

    // U direct-load pointers: thread (mt, pp) owns tb pair {2pp, 2pp+1}
    int mt = tid & 15, pp = tid >> 4;
    int tb0 = 2 * pp, tb1 = 2 * pp + 1;
    const float2* up0 = usrc + (size_t)(tb0 >> 2) * 131072
                        + (size_t)(tb0 & 3) * 32768 + half * 256 + m0 + mt;
    const float2* up1 = usrc + (size_t)(tb1 >> 2) * 131072
                        + (size_t)(tb1 & 3) * 32768 + half * 256 + m0 + mt;

    float aR[8][2], aI[8][2];
    #pragma unroll
    for (int oo = 0; oo < 8; oo++) {
        aR[oo][0] = 0.f; aR[oo][1] = 0.f;
        aI[oo][0] = 0.f; aI[oo][1] = 0.f;
    }

    // prologue: stage W chunk 0 into buf0, prefetch W chunk 1
    float4 wv = wg4[0];
    Wl[0][(wii * 16 + 2 * wl) * 10 + woo]     = make_float2(wv.x, wv.y);
    Wl[0][(wii * 16 + 2 * wl + 1) * 10 + woo] = make_float2(wv.z, wv.w);
    wv = wg4[32768];
    __syncthreads();

    for (int c = 0; c < 16; ++c) {
        int cb = c & 1;
        // U for THIS chunk: 8 direct global loads (drain at end-of-iter barrier)
        float2 u0v[4], u1v[4];
        #pragma unroll
        for (int ii = 0; ii < 4; ii++) {
            u0v[ii] = up0[(size_t)(4 * c + ii) * 512];
            u1v[ii] = up1[(size_t)(4 * c + ii) * 512];
        }
        // stage NEXT chunk's W into the other buffer (safe: nobody reads it)
        if (c < 15) {
            Wl[cb ^ 1][(wii * 16 + 2 * wl) * 10 + woo]     = make_float2(wv.x, wv.y);
            Wl[cb ^ 1][(wii * 16 + 2 * wl + 1) * 10 + woo] = make_float2(wv.z, wv.w);
            if (c < 14) wv = wg4[(size_t)(c + 2) * 32768];
        }
        // compute chunk c from buf cb
        #pragma unroll
        for (int ii = 0; ii < 4; ii++) {
            const float2* wrow2 = &Wl[cb][(ii * 16 + mt) * 10];
            float4 wq0 = *(const float4*)(wrow2 + 0);   // oo 0,1
            float4 wq1 = *(const float4*)(wrow2 + 2);   // oo 2,3
            float4 wq2 = *(const float4*)(wrow2 + 4);   // oo 4,5
            float4 wq3 = *(const float4*)(wrow2 + 6);   // oo 6,7
            float2 u0 = u0v[ii], u1 = u1v[ii];
            float2 wz[8];
            wz[0] = make_float2(wq0.x, wq0.y); wz[1] = make_float2(wq0.z, wq0.w);
            wz[2] = make_float2(wq1.x, wq1.y); wz[3] = make_float2(wq1.z, wq1.w);
            wz[4] = make_float2(wq2.x, wq2.y); wz[5] = make_float2(wq2.z, wq2.w);
            wz[6] = make_float2(wq3.x, wq3.y); wz[7] = make_float2(wq3.z, wq3.w);
            #pragma unroll
            for (int oo = 0; oo < 8; oo++) {
                float2 w = wz[oo];
                aR[oo][0] = fmaf(u0.x, w.x, aR[oo][0]);
                aR[oo][0] = fmaf(-u0.y, w.y, aR[oo][0]);
                aI[oo][0] = fmaf(u0.x, w.y, aI[oo][0]);
                aI[oo][0] = fmaf(u0.y, w.x, aI[oo][0]);
                aR[oo][1] = fmaf(u1.x, w.x, aR[oo][1]);
                aR[oo][1] = fmaf(-u1.y, w.y, aR[oo][1]);
                aI[oo][1] = fmaf(u1.x, w.y, aI[oo][1]);
                aI[oo][1] = fmaf(u1.y, w.x, aI[oo][1]);
            }
        }
        __syncthreads();   // publishes buf cb^1 writes; gates next compute
    }

    // epilogue: write Sx (same layout as rounds 0-4)
    float2* S2 = (float2*)Sx;
    #pragma unroll
    for (int oo = 0; oo < 8; oo++)
        #pragma unroll
        for (int j = 0; j < 2; j++) {
            int tb = 2 * pp + j;
            int t = tb >> 2, b = tb & 3;
            S2[((size_t)(li * 8 + t) * 256 + b * 64 + o0 + oo) * 512
               + half * 256 + m0 + mt] = make_float2(aR[oo][j], aI[oo][j]);
        }
}

// ---------------- per-step h-side mix body --------------------------------------
// blk bits: [g][half][ic(8)][og(16)]; 8 i per block.
// Spart layout: [(g*8+ic)*256 + b*64+o][UMAP]
__device__ __forceinline__ void mix_body_h(int blk, int l0, int l1,
    const float* __restrict__ U,
    const float* __restrict__ sw1, const float* __restrict__ sw2,
    float* __restrict__ Spart)
{
    int og = blk & 15;
    int ic = (blk >> 4) & 7;
    int half = (blk >> 7) & 1;
    int g = (blk >> 8) & 1;
    int m = threadIdx.x;
    int o0 = og * 4, ib = ic * 8;
    int l = g ? l1 : l0;
    const float2* wt = (const float2*)(half ? sw2 : sw1);
    const float2* W2 = wt + (((size_t)l * 64 + ib) * 64 + o0) * 256 + m;
    const float2* U2 = (const float2*)U + (size_t)ib * 512 + half * 256 + m;
    float aR[4][4], aI[4][4];
    #pragma unroll
    for (int oo = 0; oo < 4; oo++)
        #pragma unroll
        for (int b = 0; b < 4; b++) { aR[oo][b] = 0.f; aI[oo][b] = 0.f; }
    mix_accum(W2, U2, 8, aR, aI);
    float2* S2 = (float2*)Spart;
    #pragma unroll
    for (int oo = 0; oo < 4; oo++)
        #pragma unroll
        for (int b = 0; b < 4; b++)
            S2[((size_t)(g * 8 + ic) * 256 + b * 64 + o0 + oo) * 512 + half * 256 + m]
                = make_float2(aR[oo][b], aI[oo][b]);
}

// ---------------- 1x1-conv skip: register-tiled GEMM ----------------------------
__device__ __forceinline__ void fma16(const float4 w, const float4 u, float acc[4][4]) {
    acc[0][0] = fmaf(u.x, w.x, acc[0][0]); acc[0][1] = fmaf(u.y, w.x, acc[0][1]);
    acc[0][2] = fmaf(u.z, w.x, acc[0][2]); acc[0][3] = fmaf(u.w, w.x, acc[0][3]);
    acc[1][0] = fmaf(u.x, w.y, acc[1][0]); acc[1][1] = fmaf(u.y, w.y, acc[1][1]);
    acc[1][2] = fmaf(u.z, w.y, acc[1][2]); acc[1][3] = fmaf(u.w, w.y, acc[1][3]);
    acc[2][0] = fmaf(u.x, w.z, acc[2][0]); acc[2][1] = fmaf(u.y, w.z, acc[2][1]);
    acc[2][2] = fmaf(u.z, w.z, acc[2][2]); acc[2][3] = fmaf(u.w, w.z, acc[2][3]);
    acc[3][0] = fmaf(u.x, w.w, acc[3][0]); acc[3][1] = fmaf(u.y, w.w, acc[3][1]);
    acc[3][2] = fmaf(u.z, w.w, acc[3][2]); acc[3][3] = fmaf(u.w, w.w, acc[3][3]);
}

__device__ __forceinline__ void skip_gemm(int rr, float* __restrict__ sW,
    const float* __restrict__ uA, long long bsA,
    const float* __restrict__ uB, long long bsB,
    const float* __restrict__ skw, int lA, int lB, float gb,
    float* __restrict__ out)
{
    int pxc = rr & 31, oh = (rr >> 5) & 1, b = rr >> 6;
    int tid = threadIdx.x;
    int ot = tid & 7, pt = tid >> 3;       // 8 o-tiles x 4o, 32 px-tiles x 4px
    #pragma unroll
    for (int n = 0; n < 4; n++) {
        int idx = n * 1024 + tid * 4;
        int k = idx >> 5, oc = idx & 31;
        int p = k >> 6, i = k & 63;
        *(float4*)(sW + idx) =
            *(const float4*)(skw + (p ? lB : lA) * 4096 + i * 64 + oh * 32 + oc);
    }
    __syncthreads();
    float acc[4][4];
    #pragma unroll
    for (int oo = 0; oo < 4; oo++)
        #pragma unroll
        for (int q = 0; q < 4; q++) acc[oo][q] = 0.f;
    const float* pa = uA + (long long)b * bsA + pxc * 128 + pt * 4;
    const float* pb = uB + (long long)b * bsB + pxc * 128 + pt * 4;
    const float4* sW4 = (const float4*)sW;   // [128][8] float4
    #pragma unroll 4
    for (int i = 0; i < 64; i++) {
        float4 ua = *(const float4*)(pa + (size_t)i * HW);
        float4 wa = sW4[i * 8 + ot];
        fma16(wa, ua, acc);
        float4 ub = *(const float4*)(pb + (size_t)i * HW);
        float4 wb = sW4[(64 + i) * 8 + ot];
        fma16(wb, ub, acc);
    }
    float* op = out + ((long long)(b * 64 + oh * 32 + ot * 4)) * HW + pxc * 128 + pt * 4;
    #pragma unroll
    for (int oo = 0; oo < 4; oo++) {
        float4 r = make_float4(acc[oo][0] + gb, acc[oo][1] + gb,
                               acc[oo][2] + gb, acc[oo][3] + gb);
        *(float4*)(op + (size_t)oo * HW) = r;
    }
}

// ---------------- inverse DFT stage 1, 256-thread variant -----------------------
__device__ __forceinline__ void idft_stage1_256(const float* __restrict__ SR,
                                                const float* __restrict__ SI,
                                                float* __restrict__ GR, float* __restrict__ GI)
{
    int tid = threadIdx.x;
    int kx = tid & 15, yb = tid >> 4;
    #pragma unroll
    for (int j = 0; j < 4; j++) {
        int y = yb + 16 * j;
        float stc, sts;
        __sincosf(STEP * (float)y, &sts, &stc);
        float ar = 0.f, ai = 0.f;
        float wr = 1.f, wi = 0.f;
        for (int k = 0; k < 16; k++) {
            float sr_ = SR[k * 16 + kx], si_ = SI[k * 16 + kx];
            ar = fmaf(sr_, wr, ar); ar = fmaf(-si_, wi, ar);
            ai = fmaf(sr_, wi, ai); ai = fmaf(si_, wr, ai);
            float t = wr * stc - wi * sts; wi = wr * sts + wi * stc; wr = t;
        }
        int q = (3 * y) & 3;
        float w2r = (q == 0) ? 1.f : ((q == 2) ? -1.f : 0.f);
        float w2i = (q == 1) ? 1.f : ((q == 3) ? -1.f : 0.f);
        for (int k = 16; k < 32; k++) {
            float sr_ = SR[k * 16 + kx], si_ = SI[k * 16 + kx];
            ar = fmaf(sr_, w2r, ar); ar = fmaf(-si_, w2i, ar);
            ai = fmaf(sr_, w2i, ai); ai = fmaf(si_, w2r, ai);
            float t = w2r * stc - w2i * sts; w2i = w2r * sts + w2i * stc; w2r = t;
        }
        GR[y * 16 + kx] = ar;
        GI[y * 16 + kx] = ai;
    }
}

// ---------------- z-gate finalize (256 thr) -- moved out of back_zr -------------
// Reads Spart slots 0..7 (written by this step's front_zr; race-free because
// front_h's mix blocks write slots 8..15) + Sx slot t; idft + sigmoid into zb.
__device__ __forceinline__ void z_finalize(int map, int t,
    const float* __restrict__ Spart, const float* __restrict__ Sx,
    float* __restrict__ zb, float* __restrict__ smem)
{
    float* SR = smem;          // 512
    float* SI = smem + 512;    // 512
    float* GR = smem + 1024;   // 1024
    float* GI = smem + 2048;   // 1024
    int tid = threadIdx.x;
    {
        float4 v = ((const float4*)Sx)[((size_t)t * 256 + map) * 256 + tid];
        float sxr = v.x, sxi = v.y, syr = v.z, syi = v.w;
        const float4* base = (const float4*)Spart;
        #pragma unroll
        for (int ic = 0; ic < 8; ic++) {
            float4 p = base[((size_t)ic * 256 + map) * 256 + tid];
            sxr += p.x; sxi += p.y; syr += p.z; syi += p.w;
        }
        SR[2 * tid] = sxr; SI[2 * tid] = sxi;
        SR[2 * tid + 1] = syr; SI[2 * tid + 1] = syi;
    }
    __syncthreads();
    idft_stage1_256(SR, SI, GR, GI);
    __syncthreads();
    int x = tid & 63, ybase = tid >> 6;
    float cx, sx;
    __sincosf(STEP * (float)x, &sx, &cx);
    size_t mo = (size_t)map * HW;
    #pragma unroll
    for (int j = 0; j < 16; j++) {
        int y = ybase + 4 * j;
        float acc = GR[y * 16];
        float wr = cx, wi = sx;
        #pragma unroll
        for (int k = 1; k < 16; k++) {
            acc = fmaf(2.f * GR[y * 16 + k], wr, acc);
            acc = fmaf(-2.f * GI[y * 16 + k], wi, acc);
            float t2 = wr * cx - wi * sx; wi = wr * sx + wi * cx; wr = t2;
        }
        float val = acc * (1.f / 64.f);
        int idx = y * 64 + x;
        float pre = val + zb[mo + idx];
        zb[mo + idx] = 1.f / (1.f + __expf(-pre));
    }
}

// ---------------- fused front kernels -------------------------------------------
__global__ __launch_bounds__(256) void k_front_zr(
    const float* __restrict__ Uh,
    const float* __restrict__ xt, const float* __restrict__ hb,
    const float* __restrict__ sw1, const float* __restrict__ sw2,
    const float* __restrict__ skw, const float* __restrict__ gate_b,
    float* __restrict__ Spart, float* __restrict__ zb, float* __restrict__ rhb)
{
    __shared__ float smem[4096];
    int blk = blockIdx.x;
    if (blk < 512) {
        mix_body_h(blk, 1, 3, Uh, sw1, sw2, Spart);
    } else {
        int r = blk - 512;
        int g = r >> 8;
        skip_gemm(r & 255, smem,
                  xt, (long long)TT_ * CC_ * HW, hb, (long long)CC_ * HW,
                  skw, g ? 2 : 0, g ? 3 : 1, gate_b[g], g ? rhb : zb);
    }
}

// front_h v6: 768 blocks = 256 z-finalize (first: longest chain) + 256 h-mix
// (writes Spart slots 8..15 -- g=1 namespace, freed by the completed back_zr)
// + 256 skip.
__global__ __launch_bounds__(256) void k_front_h(
    const float* __restrict__ Urh,
    const float* __restrict__ xt, const float* __restrict__ rhb,
    const float* __restrict__ sw1, const float* __restrict__ sw2,
    const float* __restrict__ skw, const float* __restrict__ gate_b,
    float* __restrict__ Spart, float* __restrict__ phb,
    const float* __restrict__ Sx, int t, float* __restrict__ zb)
{
    __shared__ float smem[4096];
    int blk = blockIdx.x;
    if (blk < 256) {
        z_finalize(blk, t, Spart, Sx, zb, smem);
    } else if (blk < 512) {
        // blk in [256,512): bits give g=1 -> writes slots 8..15
        mix_body_h(blk, 5, 5, Urh, sw1, sw2, Spart);
    } else {
        int r = blk - 512;
        skip_gemm(r, smem,
                  xt, (long long)TT_ * CC_ * HW, rhb, (long long)CC_ * HW,
                  skw, 4, 5, gate_b[2], phb);
    }
}

// ---------------- inverse DFT stage 1, 512-thread variant -----------------------
__device__ __forceinline__ void idft_stage1_512(const float* __restrict__ SR,
                                                const float* __restrict__ SI,
                                                float* __restrict__ GR, float* __restrict__ GI)
{
    int tid = threadIdx.x;
    int kx = tid & 15, yb = tid >> 4;        // yb 0..31
    #pragma unroll
    for (int j = 0; j < 2; j++) {
        int y = yb + 32 * j;
        float stc, sts;
        __sincosf(STEP * (float)y, &sts, &stc);
        float ar = 0.f, ai = 0.f;
        float wr = 1.f, wi = 0.f;
        for (int k = 0; k < 16; k++) {
            float sr_ = SR[k * 16 + kx], si_ = SI[k * 16 + kx];
            ar = fmaf(sr_, wr, ar); ar = fmaf(-si_, wi, ar);
            ai = fmaf(sr_, wi, ai); ai = fmaf(si_, wr, ai);
            float t = wr * stc - wi * sts; wi = wr * sts + wi * stc; wr = t;
        }
        int q = (3 * y) & 3;
        float w2r = (q == 0) ? 1.f : ((q == 2) ? -1.f : 0.f);
        float w2i = (q == 1) ? 1.f : ((q == 3) ? -1.f : 0.f);
        for (int k = 16; k < 32; k++) {
            float sr_ = SR[k * 16 + kx], si_ = SI[k * 16 + kx];
            ar = fmaf(sr_, w2r, ar); ar = fmaf(-si_, w2i, ar);
            ai = fmaf(sr_, w2i, ai); ai = fmaf(si_, w2r, ai);
            float t = w2r * stc - w2i * sts; w2i = w2r * sts + w2i * stc; w2r = t;
        }
        GR[y * 16 + kx] = ar;
        GI[y * 16 + kx] = ai;
    }
}

// ---------------- back kernel zr (512 thr): r-gate only now ---------------------
__global__ __launch_bounds__(512) void k_back_zr(
    const float* __restrict__ Spart, const float* __restrict__ Sx, int t,
    float* __restrict__ rhb,
    const float* __restrict__ hb, float* __restrict__ Urh)
{
    __shared__ float smem[6208];
    float* SR = smem;          // 512
    float* SI = smem + 512;    // 512
    float* GR = smem + 1024;   // 1024
    float* GI = smem + 2048;   // 1024
    int map = blockIdx.x;
    int tid = threadIdx.x;
    {
        float2 v = ((const float2*)Sx)[((size_t)(8 + t) * 256 + map) * 512 + tid];
        float sr = v.x, si = v.y;
        const float2* base = (const float2*)Spart;
        #pragma unroll
        for (int ic = 0; ic < 8; ic++) {
            float2 p = base[((size_t)(8 + ic) * 256 + map) * 512 + tid];
            sr += p.x; si += p.y;
        }
        SR[tid] = sr; SI[tid] = si;
    }
    __syncthreads();
    idft_stage1_512(SR, SI, GR, GI);
    __syncthreads();
    int x = tid & 63, ybase = tid >> 6;      // ybase 0..7
    float cx, sx;
    __sincosf(STEP * (float)x, &sx, &cx);
    size_t mo = (size_t)map * HW;
    float rhv[8];
    #pragma unroll
    for (int j = 0; j < 8; j++) {
        int y = ybase + 8 * j;
        float acc = GR[y * 16];
        float wr = cx, wi = sx;
        #pragma unroll
        for (int k = 1; k < 16; k++) {
            acc = fmaf(2.f * GR[y * 16 + k], wr, acc);
            acc = fmaf(-2.f * GI[y * 16 + k], wi, acc);
            float t2 = wr * cx - wi * sx; wi = wr * sx + wi * cx; wr = t2;
        }
        float val = acc * (1.f / 64.f);
        int idx = y * 64 + x;
        float pre = val + rhb[mo + idx];
        float rr = 1.f / (1.f + __expf(-pre));
        float rh = rr * hb[mo + idx];
        rhb[mo + idx] = rh;
        rhv[j] = rh;
    }
    __syncthreads();
    float* su = smem;
    #pragma unroll
    for (int j = 0; j < 8; j++) {
        int y = ybase + 8 * j;
        su[y * 65 + x] = rhv[j];
    }
    __syncthreads();
    dft_stages_512(su, smem + 4160, smem + 5184, Urh + (size_t)map * UMAP);
}

// ---------------- back kernel h (512 thr): idft + GRU update + fused h DFT ------
__global__ __launch_bounds__(512) void k_back_h(
    const float* __restrict__ Spart, const float* __restrict__ Sx, int t,
    const float* __restrict__ zb, const float* __restrict__ phb,
    float* __restrict__ hb, float* __restrict__ Uh)
{
    __shared__ float smem[6208];
    float* SR = smem;
    float* SI = smem + 512;
    float* GR = smem + 1024;
    float* GI = smem + 2048;
    int map = blockIdx.x & 255;
    int tid = threadIdx.x;
    {
        float2 v = ((const float2*)Sx)[((size_t)(2 * 8 + t) * 256 + map) * 512 + tid];
        float sr = v.x, si = v.y;
        const float2* base = (const float2*)Spart;
        #pragma unroll
        for (int ic = 0; ic < 8; ic++) {
            float2 p = base[((size_t)(8 + ic) * 256 + map) * 512 + tid];
            sr += p.x; si += p.y;
        }
        SR[tid] = sr; SI[tid] = si;
    }
    __syncthreads();
    idft_stage1_512(SR, SI, GR, GI);
    __syncthreads();
    int x = tid & 63, ybase = tid >> 6;
    float cx, sx;
    __sincosf(STEP * (float)x, &sx, &cx);
    size_t mo = (size_t)map * HW;
    float hv[8];
    #pragma unroll
    for (int j = 0; j < 8; j++) {
        int y = ybase + 8 * j;
        float acc = GR[y * 16];
        float wr = cx, wi = sx;
        #pragma unroll
        for (int k = 1; k < 16; k++) {
            acc = fmaf(2.f * GR[y * 16 + k], wr, acc);
            acc = fmaf(-2.f * GI[y * 16 + k], wi, acc);
            float t2 = wr * cx - wi * sx; wi = wr * sx + wi * cx; wr = t2;
        }
        float val = acc * (1.f / 64.f);
        int idx = y * 64 + x;
        float pre = val + phb[mo + idx];
        float hh = (pre > 0.f) ? 1.0507009873554805f * pre
                               : 1.7580993408473766f * (__expf(pre) - 1.f);
        float z = zb[mo + idx];
        float hn = fmaf(z, hh - hb[mo + idx], hb[mo + idx]);
        hb[mo + idx] = hn;
        hv[j] = hn;
    }
    __syncthreads();
    float* su = smem;
    #pragma unroll
    for (int j = 0; j < 8; j++) {
        int y = ybase + 8 * j;
        su[y * 65 + x] = hv[j];
    }
    __syncthreads();
    dft_stages_512(su, smem + 4160, smem + 5184, Uh + (size_t)map * UMAP);
}

extern "C" void kernel_launch(void* const* d_in, const int* in_sizes, int n_in,
                              void* d_out, int out_size, void* d_ws, size_t ws_size,
                              hipStream_t stream)
{
    (void)in_sizes; (void)n_in; (void)out_size; (void)ws_size;
    const float* x   = (const float*)d_in[0];
    const float* sw1 = (const float*)d_in[1];
    const float* sw2 = (const float*)d_in[2];
    const float* skw = (const float*)d_in[3];
    const float* gb  = (const float*)d_in[4];
    const float* bh  = (const float*)d_in[5];
    float* ws    = (float*)d_ws;
    float* Uxall = ws + OFF_UXALL;
    float* Uh    = ws + OFF_UH;
    float* Urh   = ws + OFF_URH;
    float* Sx    = ws + OFF_SX;
    float* Sp    = ws + OFF_SPART;
    float* hb    = ws + OFF_H;
    float* zb    = ws + OFF_Z;
    float* rhb   = ws + OFF_RH;
    float* phb   = ws + OFF_PH;

    k_init<<<1280, 256, 0, stream>>>(hb, Uh, bh);
    k_dft_x<<<2048, 256, 0, stream>>>(x, Uxall);
    k_mix_x<<<768, 256, 0, stream>>>(Uxall, sw1, sw2, Sx);
    for (int t = 0; t < TT_; t++) {
        const float* xt = x + (size_t)t * CC_ * HW;
        k_front_zr<<<1024, 256, 0, stream>>>(Uh, xt, hb, sw1, sw2, skw, gb,
                                             Sp, zb, rhb);
        k_back_zr<<<256, 512, 0, stream>>>(Sp, Sx, t, rhb, hb, Urh);
        k_front_h<<<768, 256, 0, stream>>>(Urh, xt, rhb, sw1, sw2, skw, gb,
                                           Sp, phb, Sx, t, zb);
        k_back_h<<<256, 512, 0, stream>>>(Sp, Sx, t, zb, phb, hb, Uh);
    }
    hipMemcpyAsync(d_out, hb, (size_t)BB_ * CC_ * HW * sizeof(float),
                   hipMemcpyDeviceToDevice, stream);
}